// Round 6
// baseline (869.712 us; speedup 1.0000x reference)
//
#include <hip/hip_runtime.h>

// ---------------------------------------------------------------------------
// GAT (5 layers, 8 heads / last 1 head) + final linear.
// GEMMs: split-bf16 (hi+lo) MFMA, fp32 accumulate. W converted ONCE per layer
// (k_cvt_w) into global transposed bf16 planes; GEMM reads them L2-hot with
// zero LDS / zero barriers. dst-CSR built once; fused online-softmax +
// aggregation per node (gathers h fp32, emits next layer's bf16 hi/lo).
// ---------------------------------------------------------------------------

typedef short short8 __attribute__((ext_vector_type(8)));
typedef float floatx4 __attribute__((ext_vector_type(4)));

__device__ __forceinline__ unsigned short f2bf(float f) {
  unsigned u = __float_as_uint(f);
  return (unsigned short)((u + 0x7FFF + ((u >> 16) & 1)) >> 16);  // RNE
}
__device__ __forceinline__ float bf2f(unsigned short h) {
  return __uint_as_float(((unsigned)h) << 16);
}

// ---------------- CSR build ----------------
__global__ __launch_bounds__(256) void k_deg_init(int* deg, int n) {
  int i = blockIdx.x * 256 + threadIdx.x;
  if (i < n) deg[i] = 1;  // self loop
}

__global__ __launch_bounds__(256) void k_count(const int* __restrict__ ei, int E, int* deg) {
  int i = blockIdx.x * 256 + threadIdx.x;
  if (i < E) atomicAdd(&deg[ei[E + i]], 1);
}

__device__ __forceinline__ int block_excl_scan(int v, int* tot) {
  __shared__ int wsum[4];
  int lane = threadIdx.x & 63, w = threadIdx.x >> 6;
  int x = v;
  #pragma unroll
  for (int off = 1; off < 64; off <<= 1) {
    int y = __shfl_up(x, off);
    if (lane >= off) x += y;
  }
  if (lane == 63) wsum[w] = x;
  __syncthreads();
  int wbase = 0;
  #pragma unroll
  for (int i = 0; i < 4; i++) wbase += (i < w) ? wsum[i] : 0;
  if (tot) *tot = wsum[0] + wsum[1] + wsum[2] + wsum[3];
  return wbase + x - v;
}

__global__ __launch_bounds__(256) void k_bsum(const int* __restrict__ deg, int* __restrict__ bsum, int n) {
  int i = blockIdx.x * 256 + threadIdx.x;
  int v = (i < n) ? deg[i] : 0;
  int tot;
  block_excl_scan(v, &tot);
  if (threadIdx.x == 0) bsum[blockIdx.x] = tot;
}

__global__ __launch_bounds__(256) void k_bscan(const int* __restrict__ bsum, int* __restrict__ boff, int nb) {
  int t = threadIdx.x;
  int v = (t < nb) ? bsum[t] : 0;
  int ex = block_excl_scan(v, nullptr);
  if (t < nb) boff[t] = ex;
}

__global__ __launch_bounds__(256) void k_rowptr(const int* __restrict__ deg,
                                                const int* __restrict__ boff,
                                                int* __restrict__ row_ptr,
                                                int* __restrict__ cursor, int n) {
  int i = blockIdx.x * 256 + threadIdx.x;
  int v = (i < n) ? deg[i] : 0;
  int ex = block_excl_scan(v, nullptr) + boff[blockIdx.x];
  if (i < n) { row_ptr[i] = ex; cursor[i] = ex; }
  if (i == n - 1) row_ptr[n] = ex + v;
}

__global__ __launch_bounds__(256) void k_fill(const int* __restrict__ ei, int E, int n,
                                              int* cursor, int* __restrict__ srcs) {
  int i = blockIdx.x * 256 + threadIdx.x;
  if (i >= E + n) return;
  int s, d;
  if (i < E) { s = ei[i]; d = ei[E + i]; }
  else       { s = i - E; d = s; }
  int slot = atomicAdd(&cursor[d], 1);
  srcs[slot] = s;
}

// ---------------- fp32 -> split-bf16 planes (x input) ----------------
__global__ __launch_bounds__(256) void k_cvt(const float* __restrict__ x,
                                             unsigned short* __restrict__ hi,
                                             unsigned short* __restrict__ lo, int n4) {
  int i = blockIdx.x * 256 + threadIdx.x;
  if (i >= n4) return;
  float4 v = ((const float4*)x)[i];
  ushort4 h, l;
  h.x = f2bf(v.x); l.x = f2bf(v.x - bf2f(h.x));
  h.y = f2bf(v.y); l.y = f2bf(v.y - bf2f(h.y));
  h.z = f2bf(v.z); l.z = f2bf(v.z - bf2f(h.z));
  h.w = f2bf(v.w); l.w = f2bf(v.w - bf2f(h.w));
  ((ushort4*)hi)[i] = h;
  ((ushort4*)lo)[i] = l;
}

// ---------------- W[k][n] fp32 -> transposed split-bf16 Wt[n][k] ----------
// Once per layer: 16 blocks x 256 thr. Tiny (64 KB out), L2-resident after.
__global__ __launch_bounds__(256) void k_cvt_w(const float* __restrict__ W,
                                               unsigned short* __restrict__ WtHi,
                                               unsigned short* __restrict__ WtLo) {
  int idx = blockIdx.x * 256 + threadIdx.x;   // 4096 threads
  int n = idx >> 5;
  int k4 = (idx & 31) << 2;
  ushort4 h, l;
  float v0 = W[(k4 + 0) * 128 + n];
  float v1 = W[(k4 + 1) * 128 + n];
  float v2 = W[(k4 + 2) * 128 + n];
  float v3 = W[(k4 + 3) * 128 + n];
  h.x = f2bf(v0); l.x = f2bf(v0 - bf2f(h.x));
  h.y = f2bf(v1); l.y = f2bf(v1 - bf2f(h.y));
  h.z = f2bf(v2); l.z = f2bf(v2 - bf2f(h.z));
  h.w = f2bf(v3); l.w = f2bf(v3 - bf2f(h.w));
  *(ushort4*)(WtHi + n * 128 + k4) = h;
  *(ushort4*)(WtLo + n * 128 + k4) = l;
}

// ---------------------------------------------------------------------------
// C[M,128] = A[M,128] @ W[128,128] (+bias,+relu) via split-bf16 MFMA.
// No LDS, no barriers. 4 waves x 16 rows = 64 rows/block.
// mfma_f32_16x16x32_bf16: A[lane&15][(lane>>4)*8+i], B[(lane>>4)*8+i][lane&15],
// C col=lane&15, row=(lane>>4)*4+reg (m89-verified layout).
// B frags read straight from Wt[n][k] (L2-hot, shared by all blocks).
// ---------------------------------------------------------------------------
__global__ __launch_bounds__(256) void k_gemm_bf(const unsigned short* __restrict__ Ahi,
                                                 const unsigned short* __restrict__ Alo,
                                                 const unsigned short* __restrict__ WtHi,
                                                 const unsigned short* __restrict__ WtLo,
                                                 const float* __restrict__ bias,
                                                 float* __restrict__ C, int M, int relu) {
  int tid = threadIdx.x;
  int lane = tid & 63;
  int wv = tid >> 6;
  int m0 = blockIdx.x * 64 + wv * 16;
  int lr = lane & 15;    // A-row within tile / B,C-col within tile
  int kb = lane >> 4;    // k sub-block (8 elems)
  int arow = m0 + lr; if (arow >= M) arow = M - 1;   // clamp (stores guarded)
  const size_t abase = (size_t)arow * 128;

  short8 ahi[4], alo[4];
  #pragma unroll
  for (int j = 0; j < 4; j++) {
    int k0 = j * 32 + kb * 8;
    ahi[j] = *(const short8*)(Ahi + abase + k0);
    alo[j] = *(const short8*)(Alo + abase + k0);
  }

  floatx4 acc[8];
  #pragma unroll
  for (int nt = 0; nt < 8; nt++) acc[nt] = (floatx4){0.f, 0.f, 0.f, 0.f};

  #pragma unroll
  for (int j = 0; j < 4; j++) {          // K step of 32
    int k0 = j * 32 + kb * 8;
    #pragma unroll
    for (int nt = 0; nt < 8; nt++) {     // N tile of 16
      int bofs = (nt * 16 + lr) * 128 + k0;
      short8 bhi = *(const short8*)(WtHi + bofs);
      short8 blo = *(const short8*)(WtLo + bofs);
      acc[nt] = __builtin_amdgcn_mfma_f32_16x16x32_bf16(ahi[j], bhi, acc[nt], 0, 0, 0);
      acc[nt] = __builtin_amdgcn_mfma_f32_16x16x32_bf16(ahi[j], blo, acc[nt], 0, 0, 0);
      acc[nt] = __builtin_amdgcn_mfma_f32_16x16x32_bf16(alo[j], bhi, acc[nt], 0, 0, 0);
    }
  }

  #pragma unroll
  for (int nt = 0; nt < 8; nt++) {
    int col = nt * 16 + lr;
    #pragma unroll
    for (int r = 0; r < 4; r++) {
      int row = m0 + kb * 4 + r;
      if (row < M) {
        float v = acc[nt][r];
        if (bias) v += bias[col];
        if (relu) v = fmaxf(v, 0.f);
        C[(size_t)row * 128 + col] = v;
      }
    }
  }
}

// ---------------- attention logits ----------------
__global__ __launch_bounds__(256) void k_al8(const float* __restrict__ h,
                                             const float* __restrict__ a_s,
                                             const float* __restrict__ a_d,
                                             float* __restrict__ als, float* __restrict__ ald, int n) {
  int g = blockIdx.x * 256 + threadIdx.x;
  if (g >= n * 8) return;
  int hd = g & 7;
  const float4* hp = (const float4*)(h + (size_t)g * 16);
  const float4* ap = (const float4*)(a_s + hd * 16);
  const float4* dp = (const float4*)(a_d + hd * 16);
  float ss = 0.f, sd = 0.f;
  #pragma unroll
  for (int i = 0; i < 4; i++) {
    float4 hv = hp[i], av = ap[i], dv = dp[i];
    ss += hv.x * av.x + hv.y * av.y + hv.z * av.z + hv.w * av.w;
    sd += hv.x * dv.x + hv.y * dv.y + hv.z * dv.z + hv.w * dv.w;
  }
  als[g] = ss; ald[g] = sd;
}

__global__ __launch_bounds__(256) void k_al1(const float* __restrict__ h,
                                             const float* __restrict__ a_s,
                                             const float* __restrict__ a_d,
                                             float* __restrict__ als, float* __restrict__ ald, int n) {
  int g = blockIdx.x * 256 + threadIdx.x;
  int v = g >> 4, q = g & 15;
  bool act = (v < n);
  float ss = 0.f, sd = 0.f;
  if (act) {
    float4 hv = *(const float4*)(h + (size_t)v * 128 + q * 4);
    float4 av = *(const float4*)(a_s + q * 4);
    float4 dv = *(const float4*)(a_d + q * 4);
    ss = hv.x * av.x + hv.y * av.y + hv.z * av.z + hv.w * av.w;
    sd = hv.x * dv.x + hv.y * dv.y + hv.z * dv.z + hv.w * dv.w;
  }
  #pragma unroll
  for (int off = 1; off < 16; off <<= 1) { ss += __shfl_xor(ss, off); sd += __shfl_xor(sd, off); }
  if (act && q == 0) { als[v] = ss; ald[v] = sd; }
}

// ---------------------------------------------------------------------------
// Fused per-node online-softmax + aggregation; one wave per destination node.
// Output written directly as split-bf16 planes (next GEMM's A).
// ---------------------------------------------------------------------------
template <int H>
__global__ __launch_bounds__(256) void k_agg(const int* __restrict__ row_ptr,
                                             const int* __restrict__ srcs,
                                             const float* __restrict__ als,
                                             const float* __restrict__ ald,
                                             const float* __restrict__ h,
                                             const float* __restrict__ bias,
                                             unsigned short* __restrict__ outHi,
                                             unsigned short* __restrict__ outLo, int n) {
  const int EPP = 64 / H;
  int lane = threadIdx.x & 63;
  int wv = threadIdx.x >> 6;
  int v = blockIdx.x * 4 + wv;
  bool active = (v < n);
  int s0 = 0, s1 = 0;
  int eo = lane / H;
  int hd = lane % H;
  float ed = 0.f;
  if (active) { s0 = row_ptr[v]; s1 = row_ptr[v + 1]; ed = ald[v * H + hd]; }
  // pass 1: online softmax (m, d)
  float m = -1e30f, d = 0.f;
  for (int j = s0 + eo; j < s1; j += EPP) {
    int sv = srcs[j];
    float e = als[sv * H + hd] + ed;
    e = (e > 0.f) ? e : 0.2f * e;
    float nm = fmaxf(m, e);
    d = d * __expf(m - nm) + __expf(e - nm);
    m = nm;
  }
  #pragma unroll
  for (int off = H; off < 64; off <<= 1) {
    float om = __shfl_xor(m, off);
    float od = __shfl_xor(d, off);
    float nm = fmaxf(m, om);
    d = d * __expf(m - nm) + od * __expf(om - nm);
    m = nm;
  }
  // pass 2: aggregation (2 edge slots x 32 channel-lanes x float4)
  int slot = lane >> 5;
  int l5 = lane & 31;
  int c0 = l5 * 4;
  int hd3 = (H == 1) ? 0 : (c0 / (128 / H));
  float m3 = __shfl(m, hd3);
  float inv = 1.f / __shfl(d, hd3);
  float ed3 = __shfl(ed, hd3);
  float ax = 0.f, ay = 0.f, az = 0.f, aw = 0.f;
  #pragma unroll 2
  for (int j = s0 + slot; j < s1; j += 2) {
    int sv = srcs[j];
    float e = als[sv * H + hd3] + ed3;
    e = (e > 0.f) ? e : 0.2f * e;
    float al = __expf(e - m3) * inv;
    float4 hv = *(const float4*)(h + (size_t)sv * 128 + c0);
    ax += al * hv.x; ay += al * hv.y; az += al * hv.z; aw += al * hv.w;
  }
  ax += __shfl_xor(ax, 32);
  ay += __shfl_xor(ay, 32);
  az += __shfl_xor(az, 32);
  aw += __shfl_xor(aw, 32);
  if (active && slot == 0) {
    float o[4];
    o[0] = fmaxf(ax + bias[c0 + 0], 0.f);
    o[1] = fmaxf(ay + bias[c0 + 1], 0.f);
    o[2] = fmaxf(az + bias[c0 + 2], 0.f);
    o[3] = fmaxf(aw + bias[c0 + 3], 0.f);
    ushort4 h4, l4;
    h4.x = f2bf(o[0]); l4.x = f2bf(o[0] - bf2f(h4.x));
    h4.y = f2bf(o[1]); l4.y = f2bf(o[1] - bf2f(h4.y));
    h4.z = f2bf(o[2]); l4.z = f2bf(o[2] - bf2f(h4.z));
    h4.w = f2bf(o[3]); l4.w = f2bf(o[3] - bf2f(h4.w));
    *(ushort4*)(outHi + (size_t)v * 128 + c0) = h4;
    *(ushort4*)(outLo + (size_t)v * 128 + c0) = l4;
  }
}

extern "C" void kernel_launch(void* const* d_in, const int* in_sizes, int n_in,
                              void* d_out, int out_size, void* d_ws, size_t ws_size,
                              hipStream_t stream) {
  const float* x  = (const float*)d_in[0];
  const int*   ei = (const int*)d_in[1];
  const int N  = in_sizes[0] / 128;
  const int E  = in_sizes[1] / 2;
  const int ET = E + N;
  const int NB = (N + 255) / 256;

  const float *Wl[5], *as[5], *ad[5], *bl[5];
  for (int l = 0; l < 5; l++) {
    Wl[l] = (const float*)d_in[3 + 4 * l];
    as[l] = (const float*)d_in[4 + 4 * l];
    ad[l] = (const float*)d_in[5 + 4 * l];
    bl[l] = (const float*)d_in[6 + 4 * l];
  }
  const float* W_lin = (const float*)d_in[23];
  const float* b_lin = (const float*)d_in[24];

  char* p = (char*)d_ws;
  auto alloc = [&](size_t bytes) { void* r = (void*)p; p += (bytes + 255) & ~size_t(255); return r; };
  float* h    = (float*)alloc((size_t)N * 128 * 4);
  unsigned short* pAhi = (unsigned short*)alloc((size_t)N * 128 * 2);
  unsigned short* pAlo = (unsigned short*)alloc((size_t)N * 128 * 2);
  unsigned short* pBhi = (unsigned short*)alloc((size_t)N * 128 * 2);
  unsigned short* pBlo = (unsigned short*)alloc((size_t)N * 128 * 2);
  unsigned short* WtHi = (unsigned short*)alloc(128 * 128 * 2);
  unsigned short* WtLo = (unsigned short*)alloc(128 * 128 * 2);
  float* als  = (float*)alloc((size_t)N * 8 * 4);
  float* ald  = (float*)alloc((size_t)N * 8 * 4);
  int* row_ptr = (int*)alloc((size_t)(N + 1) * 4);
  int* cursor  = (int*)alloc((size_t)N * 4);
  int* deg     = (int*)alloc((size_t)N * 4);
  int* srcs    = (int*)alloc((size_t)ET * 4);
  int* bsum    = (int*)alloc((size_t)NB * 4);
  int* boff    = (int*)alloc((size_t)NB * 4);
  (void)ws_size; (void)n_in; (void)out_size;

  dim3 b256(256);
  // CSR build (once; reused across all 5 layers)
  k_deg_init<<<NB, b256, 0, stream>>>(deg, N);
  k_count<<<(E + 255) / 256, b256, 0, stream>>>(ei, E, deg);
  k_bsum<<<NB, b256, 0, stream>>>(deg, bsum, N);
  k_bscan<<<1, b256, 0, stream>>>(bsum, boff, NB);
  k_rowptr<<<NB, b256, 0, stream>>>(deg, boff, row_ptr, cursor, N);
  k_fill<<<(ET + 255) / 256, b256, 0, stream>>>(ei, E, N, cursor, srcs);

  // x -> split-bf16 planes
  int n4 = N * 128 / 4;
  k_cvt<<<(n4 + 255) / 256, b256, 0, stream>>>(x, pAhi, pAlo, n4);

  int gemm_grid = (N + 63) / 64;
  unsigned short *inHi = pAhi, *inLo = pAlo, *outHi = pBhi, *outLo = pBlo;
  for (int l = 0; l < 5; l++) {
    k_cvt_w<<<16, b256, 0, stream>>>(Wl[l], WtHi, WtLo);
    k_gemm_bf<<<gemm_grid, b256, 0, stream>>>(inHi, inLo, WtHi, WtLo, nullptr, h, N, 0);
    if (l < 4) {
      k_al8<<<(N * 8 + 255) / 256, b256, 0, stream>>>(h, as[l], ad[l], als, ald, N);
      k_agg<8><<<(N + 3) / 4, b256, 0, stream>>>(row_ptr, srcs, als, ald, h, bl[l], outHi, outLo, N);
    } else {
      k_al1<<<(N * 16 + 255) / 256, b256, 0, stream>>>(h, as[l], ad[l], als, ald, N);
      k_agg<1><<<(N + 3) / 4, b256, 0, stream>>>(row_ptr, srcs, als, ald, h, bl[l], outHi, outLo, N);
    }
    unsigned short* t;
    t = inHi; inHi = outHi; outHi = t;
    t = inLo; inLo = outLo; outLo = t;
  }
  k_cvt_w<<<16, b256, 0, stream>>>(W_lin, WtHi, WtLo);
  k_gemm_bf<<<gemm_grid, b256, 0, stream>>>(inHi, inLo, WtHi, WtLo, b_lin, (float*)d_out, N, 1);
}

// Round 7
// 829.805 us; speedup vs baseline: 1.0481x; 1.0481x over previous
//
#include <hip/hip_runtime.h>

// ---------------------------------------------------------------------------
// GAT (5 layers, 8 heads / last 1 head) + final linear.
// - GEMM: split-bf16 (hi+lo) MFMA, fp32 accumulate. Wt extended to 144 cols
//   [W | W@Ms | W@Md] so attention logits als/ald are GEMM outputs (tile nt=8).
//   Wt stored in fragment-contiguous swizzled layout -> every B load is a
//   64-lane x 16B contiguous 1KB burst.
// - k_agg: LDS-cached logits -> alpha computed once per (edge,head); pass 2
//   gathers h one edge-row at a time with all 64 lanes (coalesced 512B).
// ---------------------------------------------------------------------------

typedef short short8 __attribute__((ext_vector_type(8)));
typedef float floatx4 __attribute__((ext_vector_type(4)));

__device__ __forceinline__ unsigned short f2bf(float f) {
  unsigned u = __float_as_uint(f);
  return (unsigned short)((u + 0x7FFF + ((u >> 16) & 1)) >> 16);  // RNE
}
__device__ __forceinline__ float bf2f(unsigned short h) {
  return __uint_as_float(((unsigned)h) << 16);
}

// ---------------- CSR build ----------------
__global__ __launch_bounds__(256) void k_deg_init(int* deg, int n) {
  int i = blockIdx.x * 256 + threadIdx.x;
  if (i < n) deg[i] = 1;  // self loop
}

__global__ __launch_bounds__(256) void k_count(const int* __restrict__ ei, int E, int* deg) {
  int i = blockIdx.x * 256 + threadIdx.x;
  if (i < E) atomicAdd(&deg[ei[E + i]], 1);
}

__device__ __forceinline__ int block_excl_scan(int v, int* tot) {
  __shared__ int wsum[4];
  int lane = threadIdx.x & 63, w = threadIdx.x >> 6;
  int x = v;
  #pragma unroll
  for (int off = 1; off < 64; off <<= 1) {
    int y = __shfl_up(x, off);
    if (lane >= off) x += y;
  }
  if (lane == 63) wsum[w] = x;
  __syncthreads();
  int wbase = 0;
  #pragma unroll
  for (int i = 0; i < 4; i++) wbase += (i < w) ? wsum[i] : 0;
  if (tot) *tot = wsum[0] + wsum[1] + wsum[2] + wsum[3];
  return wbase + x - v;
}

__global__ __launch_bounds__(256) void k_bsum(const int* __restrict__ deg, int* __restrict__ bsum, int n) {
  int i = blockIdx.x * 256 + threadIdx.x;
  int v = (i < n) ? deg[i] : 0;
  int tot;
  block_excl_scan(v, &tot);
  if (threadIdx.x == 0) bsum[blockIdx.x] = tot;
}

__global__ __launch_bounds__(256) void k_bscan(const int* __restrict__ bsum, int* __restrict__ boff, int nb) {
  int t = threadIdx.x;
  int v = (t < nb) ? bsum[t] : 0;
  int ex = block_excl_scan(v, nullptr);
  if (t < nb) boff[t] = ex;
}

__global__ __launch_bounds__(256) void k_rowptr(const int* __restrict__ deg,
                                                const int* __restrict__ boff,
                                                int* __restrict__ row_ptr,
                                                int* __restrict__ cursor, int n) {
  int i = blockIdx.x * 256 + threadIdx.x;
  int v = (i < n) ? deg[i] : 0;
  int ex = block_excl_scan(v, nullptr) + boff[blockIdx.x];
  if (i < n) { row_ptr[i] = ex; cursor[i] = ex; }
  if (i == n - 1) row_ptr[n] = ex + v;
}

__global__ __launch_bounds__(256) void k_fill(const int* __restrict__ ei, int E, int n,
                                              int* cursor, int* __restrict__ srcs) {
  int i = blockIdx.x * 256 + threadIdx.x;
  if (i >= E + n) return;
  int s, d;
  if (i < E) { s = ei[i]; d = ei[E + i]; }
  else       { s = i - E; d = s; }
  int slot = atomicAdd(&cursor[d], 1);
  srcs[slot] = s;
}

// ---------------- fp32 -> split-bf16 planes (x input) ----------------
__global__ __launch_bounds__(256) void k_cvt(const float* __restrict__ x,
                                             unsigned short* __restrict__ hi,
                                             unsigned short* __restrict__ lo, int n4) {
  int i = blockIdx.x * 256 + threadIdx.x;
  if (i >= n4) return;
  float4 v = ((const float4*)x)[i];
  ushort4 h, l;
  h.x = f2bf(v.x); l.x = f2bf(v.x - bf2f(h.x));
  h.y = f2bf(v.y); l.y = f2bf(v.y - bf2f(h.y));
  h.z = f2bf(v.z); l.z = f2bf(v.z - bf2f(h.z));
  h.w = f2bf(v.w); l.w = f2bf(v.w - bf2f(h.w));
  ((ushort4*)hi)[i] = h;
  ((ushort4*)lo)[i] = l;
}

// ---------------------------------------------------------------------------
// Build extended, fragment-swizzled weight planes.
// Ext matrix Wext[k][n], n in [0,144):
//   n<128          : W[k][n]
//   n=128+hh       : sum_c W[k][hh*C+c]*a_src[hh][c]   (hh<H)
//   n=128+H+hh     : sum_c W[k][hh*C+c]*a_dst[hh][c]
//   else           : 0
// Storage: element (n,k): nt=n/16, lr=n%16, j=k/32, kb=(k%32)/8, e=k%8,
//   off = ((j*9+nt)*64 + kb*16+lr)*8 + e   -> B-frag load = contiguous 1KB.
// ---------------------------------------------------------------------------
__global__ __launch_bounds__(256) void k_cvt_w(const float* __restrict__ W,
                                               const float* __restrict__ a_s,
                                               const float* __restrict__ a_d,
                                               unsigned short* __restrict__ hi2,
                                               unsigned short* __restrict__ lo2, int H) {
  int t = blockIdx.x * 256 + threadIdx.x;   // 144*32 = 4608 threads
  if (t >= 144 * 32) return;
  int n = t >> 5;
  int k4 = (t & 31) << 2;
  int C = (H > 0) ? (128 / H) : 0;
  float v[4];
  #pragma unroll
  for (int e = 0; e < 4; e++) {
    int k = k4 + e;
    float val = 0.f;
    if (n < 128) {
      val = W[k * 128 + n];
    } else if (H > 0 && n < 128 + H) {
      int hh = n - 128;
      float s = 0.f;
      for (int c = 0; c < C; c++) s += W[k * 128 + hh * C + c] * a_s[hh * C + c];
      val = s;
    } else if (H > 0 && n < 128 + 2 * H) {
      int hh = n - 128 - H;
      float s = 0.f;
      for (int c = 0; c < C; c++) s += W[k * 128 + hh * C + c] * a_d[hh * C + c];
      val = s;
    }
    v[e] = val;
  }
  int nt = n >> 4, lr = n & 15;
  int j = k4 >> 5, kb = (k4 >> 3) & 3;
  int off = ((j * 9 + nt) * 64 + kb * 16 + lr) * 8 + (k4 & 7);
  ushort4 h4, l4;
  h4.x = f2bf(v[0]); l4.x = f2bf(v[0] - bf2f(h4.x));
  h4.y = f2bf(v[1]); l4.y = f2bf(v[1] - bf2f(h4.y));
  h4.z = f2bf(v[2]); l4.z = f2bf(v[2] - bf2f(h4.z));
  h4.w = f2bf(v[3]); l4.w = f2bf(v[3] - bf2f(h4.w));
  *(ushort4*)(hi2 + off) = h4;
  *(ushort4*)(lo2 + off) = l4;
}

// ---------------------------------------------------------------------------
// C[M,128] = A[M,128] @ W (+bias,+relu), als/ald from ext tile nt=8.
// Split-bf16 MFMA, no LDS, no barriers. 4 waves x 16 rows = 64 rows/block.
// mfma_f32_16x16x32_bf16: A[lane&15][(lane>>4)*8+i], B[(lane>>4)*8+i][lane&15],
// C col=lane&15, row=(lane>>4)*4+reg (m89-verified layout).
// ---------------------------------------------------------------------------
__global__ __launch_bounds__(256) void k_gemm_bf(const unsigned short* __restrict__ Ahi,
                                                 const unsigned short* __restrict__ Alo,
                                                 const unsigned short* __restrict__ hi2,
                                                 const unsigned short* __restrict__ lo2,
                                                 const float* __restrict__ bias,
                                                 float* __restrict__ C,
                                                 float* __restrict__ als,
                                                 float* __restrict__ ald,
                                                 int M, int H, int relu) {
  int tid = threadIdx.x;
  int lane = tid & 63;
  int wv = tid >> 6;
  int m0 = blockIdx.x * 64 + wv * 16;
  int lr = lane & 15;
  int kb = lane >> 4;
  int arow = m0 + lr; if (arow >= M) arow = M - 1;
  const size_t abase = (size_t)arow * 128;

  short8 ahi[4], alo[4];
  #pragma unroll
  for (int j = 0; j < 4; j++) {
    int k0 = j * 32 + kb * 8;
    ahi[j] = *(const short8*)(Ahi + abase + k0);
    alo[j] = *(const short8*)(Alo + abase + k0);
  }

  floatx4 acc[9];
  #pragma unroll
  for (int nt = 0; nt < 9; nt++) acc[nt] = (floatx4){0.f, 0.f, 0.f, 0.f};

  #pragma unroll
  for (int j = 0; j < 4; j++) {
    #pragma unroll
    for (int nt = 0; nt < 9; nt++) {
      int boff = ((j * 9 + nt) * 64 + lane) * 8;
      short8 bhi = *(const short8*)(hi2 + boff);
      short8 blo = *(const short8*)(lo2 + boff);
      acc[nt] = __builtin_amdgcn_mfma_f32_16x16x32_bf16(ahi[j], bhi, acc[nt], 0, 0, 0);
      acc[nt] = __builtin_amdgcn_mfma_f32_16x16x32_bf16(ahi[j], blo, acc[nt], 0, 0, 0);
      acc[nt] = __builtin_amdgcn_mfma_f32_16x16x32_bf16(alo[j], bhi, acc[nt], 0, 0, 0);
    }
  }

  #pragma unroll
  for (int nt = 0; nt < 8; nt++) {
    int col = nt * 16 + lr;
    #pragma unroll
    for (int r = 0; r < 4; r++) {
      int row = m0 + kb * 4 + r;
      if (row < M) {
        float v = acc[nt][r];
        if (bias) v += bias[col];
        if (relu) v = fmaxf(v, 0.f);
        C[(size_t)row * 128 + col] = v;
      }
    }
  }
  if (als) {
    #pragma unroll
    for (int r = 0; r < 4; r++) {
      int row = m0 + kb * 4 + r;
      if (row < M) {
        float v = acc[8][r];
        if (H == 8) {
          if (lr < 8) als[row * 8 + lr] = v;
          else        ald[row * 8 + (lr - 8)] = v;
        } else {
          if (lr == 0) als[row] = v;
          else if (lr == 1) ald[row] = v;
        }
      }
    }
  }
}

// ---------------------------------------------------------------------------
// Fused per-node softmax + aggregation, v2. One wave per destination node.
// pass 1: per-(edge,head) logits e -> LDS (deg<=128), online (m,d) reduce.
// pass 1.5: LDS e -> alpha in place (exp computed ONCE per (edge,head)).
// pass 2: per edge, all 64 lanes gather the 512B h row (float2/lane),
//         alpha via LDS broadcast; no cross-lane reduce at the end.
// deg>128 tail: recompute path (statistically never for Poisson(17)).
// ---------------------------------------------------------------------------
template <int H>
__global__ __launch_bounds__(256) void k_agg(const int* __restrict__ row_ptr,
                                             const int* __restrict__ srcs,
                                             const float* __restrict__ als,
                                             const float* __restrict__ ald,
                                             const float* __restrict__ h,
                                             const float* __restrict__ bias,
                                             unsigned short* __restrict__ outHi,
                                             unsigned short* __restrict__ outLo, int n) {
  __shared__ float eL[4][128 * H];
  __shared__ int svL[4][128];
  const int EPP = 64 / H;
  int lane = threadIdx.x & 63;
  int wv = threadIdx.x >> 6;
  int v = blockIdx.x * 4 + wv;
  bool active = (v < n);
  int s0 = 0, s1 = 0;
  int eo = lane / H;
  int hd = lane % H;
  float ed = 0.f;
  if (active) { s0 = row_ptr[v]; s1 = row_ptr[v + 1]; ed = ald[v * H + hd]; }
  // pass 1: logits -> LDS, online (m,d)
  float m = -1e30f, d = 0.f;
  for (int j = s0 + eo; j < s1; j += EPP) {
    int sv = srcs[j];
    float e = als[sv * H + hd] + ed;
    e = (e > 0.f) ? e : 0.2f * e;
    int idx = j - s0;
    if (idx < 128) {
      eL[wv][idx * H + hd] = e;
      if (hd == 0) svL[wv][idx] = sv;
    }
    float nm = fmaxf(m, e);
    d = d * __expf(m - nm) + __expf(e - nm);
    m = nm;
  }
  #pragma unroll
  for (int off = H; off < 64; off <<= 1) {
    float om = __shfl_xor(m, off);
    float od = __shfl_xor(d, off);
    float nm = fmaxf(m, om);
    d = d * __expf(m - nm) + od * __expf(om - nm);
    m = nm;
  }
  float inv = 1.f / d;  // d >= 1 (self loop)
  // pass 1.5: e -> alpha in place (t % H == hd since H divides 64)
  int nE = min(s1 - s0, 128);
  for (int t = lane; t < nE * H; t += 64)
    eL[wv][t] = __expf(eL[wv][t] - m) * inv;
  // pass 2: uniform-row aggregation; lane owns channels c, c+1
  int c = lane * 2;
  int hd2 = (H == 8) ? (lane >> 3) : 0;
  float m2 = __shfl(m, hd2), inv2 = __shfl(inv, hd2), ed2 = __shfl(ed, hd2);
  float a0 = 0.f, a1 = 0.f;
  for (int jj = 0; jj < nE; ++jj) {
    int sv = svL[wv][jj];
    float al = eL[wv][jj * H + hd2];
    float2 hv = *(const float2*)(h + (size_t)sv * 128 + c);
    a0 += al * hv.x; a1 += al * hv.y;
  }
  for (int j = s0 + 128; j < s1; ++j) {  // rare tail
    int sv = srcs[j];
    float e = als[sv * H + hd2] + ed2;
    e = (e > 0.f) ? e : 0.2f * e;
    float al = __expf(e - m2) * inv2;
    float2 hv = *(const float2*)(h + (size_t)sv * 128 + c);
    a0 += al * hv.x; a1 += al * hv.y;
  }
  if (active) {
    a0 = fmaxf(a0 + bias[c], 0.f);
    a1 = fmaxf(a1 + bias[c + 1], 0.f);
    ushort2 h2, l2;
    h2.x = f2bf(a0); l2.x = f2bf(a0 - bf2f(h2.x));
    h2.y = f2bf(a1); l2.y = f2bf(a1 - bf2f(h2.y));
    *(ushort2*)(outHi + (size_t)v * 128 + c) = h2;
    *(ushort2*)(outLo + (size_t)v * 128 + c) = l2;
  }
}

extern "C" void kernel_launch(void* const* d_in, const int* in_sizes, int n_in,
                              void* d_out, int out_size, void* d_ws, size_t ws_size,
                              hipStream_t stream) {
  const float* x  = (const float*)d_in[0];
  const int*   ei = (const int*)d_in[1];
  const int N  = in_sizes[0] / 128;
  const int E  = in_sizes[1] / 2;
  const int ET = E + N;
  const int NB = (N + 255) / 256;

  const float *Wl[5], *as[5], *ad[5], *bl[5];
  for (int l = 0; l < 5; l++) {
    Wl[l] = (const float*)d_in[3 + 4 * l];
    as[l] = (const float*)d_in[4 + 4 * l];
    ad[l] = (const float*)d_in[5 + 4 * l];
    bl[l] = (const float*)d_in[6 + 4 * l];
  }
  const float* W_lin = (const float*)d_in[23];
  const float* b_lin = (const float*)d_in[24];

  char* p = (char*)d_ws;
  auto alloc = [&](size_t bytes) { void* r = (void*)p; p += (bytes + 255) & ~size_t(255); return r; };
  float* h    = (float*)alloc((size_t)N * 128 * 4);
  unsigned short* pAhi = (unsigned short*)alloc((size_t)N * 128 * 2);
  unsigned short* pAlo = (unsigned short*)alloc((size_t)N * 128 * 2);
  unsigned short* pBhi = (unsigned short*)alloc((size_t)N * 128 * 2);
  unsigned short* pBlo = (unsigned short*)alloc((size_t)N * 128 * 2);
  unsigned short* WtHi = (unsigned short*)alloc(144 * 128 * 2);
  unsigned short* WtLo = (unsigned short*)alloc(144 * 128 * 2);
  float* als  = (float*)alloc((size_t)N * 8 * 4);
  float* ald  = (float*)alloc((size_t)N * 8 * 4);
  int* row_ptr = (int*)alloc((size_t)(N + 1) * 4);
  int* cursor  = (int*)alloc((size_t)N * 4);
  int* deg     = (int*)alloc((size_t)N * 4);
  int* srcs    = (int*)alloc((size_t)ET * 4);
  int* bsum    = (int*)alloc((size_t)NB * 4);
  int* boff    = (int*)alloc((size_t)NB * 4);
  (void)ws_size; (void)n_in; (void)out_size;

  dim3 b256(256);
  // CSR build (once; reused across all 5 layers)
  k_deg_init<<<NB, b256, 0, stream>>>(deg, N);
  k_count<<<(E + 255) / 256, b256, 0, stream>>>(ei, E, deg);
  k_bsum<<<NB, b256, 0, stream>>>(deg, bsum, N);
  k_bscan<<<1, b256, 0, stream>>>(bsum, boff, NB);
  k_rowptr<<<NB, b256, 0, stream>>>(deg, boff, row_ptr, cursor, N);
  k_fill<<<(ET + 255) / 256, b256, 0, stream>>>(ei, E, N, cursor, srcs);

  // x -> split-bf16 planes
  int n4 = N * 128 / 4;
  k_cvt<<<(n4 + 255) / 256, b256, 0, stream>>>(x, pAhi, pAlo, n4);

  int gemm_grid = (N + 63) / 64;
  unsigned short *inHi = pAhi, *inLo = pAlo, *outHi = pBhi, *outLo = pBlo;
  for (int l = 0; l < 5; l++) {
    int H = (l < 4) ? 8 : 1;
    k_cvt_w<<<18, b256, 0, stream>>>(Wl[l], as[l], ad[l], WtHi, WtLo, H);
    k_gemm_bf<<<gemm_grid, b256, 0, stream>>>(inHi, inLo, WtHi, WtLo, nullptr,
                                              h, als, ald, N, H, 0);
    if (l < 4)
      k_agg<8><<<(N + 3) / 4, b256, 0, stream>>>(row_ptr, srcs, als, ald, h, bl[l], outHi, outLo, N);
    else
      k_agg<1><<<(N + 3) / 4, b256, 0, stream>>>(row_ptr, srcs, als, ald, h, bl[l], outHi, outLo, N);
    unsigned short* t;
    t = inHi; inHi = outHi; outHi = t;
    t = inLo; inLo = outLo; outLo = t;
  }
  k_cvt_w<<<18, b256, 0, stream>>>(W_lin, nullptr, nullptr, WtHi, WtLo, 0);
  k_gemm_bf<<<gemm_grid, b256, 0, stream>>>(inHi, inLo, WtHi, WtLo, b_lin,
                                            (float*)d_out, nullptr, nullptr, N, 0, 1);
}

// Round 8
// 717.884 us; speedup vs baseline: 1.2115x; 1.1559x over previous
//
#include <hip/hip_runtime.h>

// ---------------------------------------------------------------------------
// GAT (5 layers, 8 heads / last 1 head) + final linear.
// - GEMM: split-bf16 (hi+lo) MFMA, fp32 accumulate. Wt extended to 144 cols
//   [W | W@Ms | W@Md] so attention logits als/ald are GEMM outputs (tile nt=8).
//   Wt stored fragment-contiguous: every B load is a 64-lane x 16B 1KB burst.
// - k_cvt_w: ONE kernel, massively parallel: blocks 0-63 transpose/split W
//   (coalesced reads, 1 elem/thread); blocks 64-95 compute projection columns
//   with one wave per k-row + segmented shfl butterfly (no serial chains).
// - k_agg: LDS-cached alpha (exp once per edge-head), uniform-row gather.
// ---------------------------------------------------------------------------

typedef short short8 __attribute__((ext_vector_type(8)));
typedef float floatx4 __attribute__((ext_vector_type(4)));

__device__ __forceinline__ unsigned short f2bf(float f) {
  unsigned u = __float_as_uint(f);
  return (unsigned short)((u + 0x7FFF + ((u >> 16) & 1)) >> 16);  // RNE
}
__device__ __forceinline__ float bf2f(unsigned short h) {
  return __uint_as_float(((unsigned)h) << 16);
}

// ---------------- CSR build ----------------
__global__ __launch_bounds__(256) void k_deg_init(int* deg, int n) {
  int i = blockIdx.x * 256 + threadIdx.x;
  if (i < n) deg[i] = 1;  // self loop
}

__global__ __launch_bounds__(256) void k_count(const int* __restrict__ ei, int E, int* deg) {
  int i = blockIdx.x * 256 + threadIdx.x;
  if (i < E) atomicAdd(&deg[ei[E + i]], 1);
}

__device__ __forceinline__ int block_excl_scan(int v, int* tot) {
  __shared__ int wsum[4];
  int lane = threadIdx.x & 63, w = threadIdx.x >> 6;
  int x = v;
  #pragma unroll
  for (int off = 1; off < 64; off <<= 1) {
    int y = __shfl_up(x, off);
    if (lane >= off) x += y;
  }
  if (lane == 63) wsum[w] = x;
  __syncthreads();
  int wbase = 0;
  #pragma unroll
  for (int i = 0; i < 4; i++) wbase += (i < w) ? wsum[i] : 0;
  if (tot) *tot = wsum[0] + wsum[1] + wsum[2] + wsum[3];
  return wbase + x - v;
}

__global__ __launch_bounds__(256) void k_bsum(const int* __restrict__ deg, int* __restrict__ bsum, int n) {
  int i = blockIdx.x * 256 + threadIdx.x;
  int v = (i < n) ? deg[i] : 0;
  int tot;
  block_excl_scan(v, &tot);
  if (threadIdx.x == 0) bsum[blockIdx.x] = tot;
}

__global__ __launch_bounds__(256) void k_bscan(const int* __restrict__ bsum, int* __restrict__ boff, int nb) {
  int t = threadIdx.x;
  int v = (t < nb) ? bsum[t] : 0;
  int ex = block_excl_scan(v, nullptr);
  if (t < nb) boff[t] = ex;
}

__global__ __launch_bounds__(256) void k_rowptr(const int* __restrict__ deg,
                                                const int* __restrict__ boff,
                                                int* __restrict__ row_ptr,
                                                int* __restrict__ cursor, int n) {
  int i = blockIdx.x * 256 + threadIdx.x;
  int v = (i < n) ? deg[i] : 0;
  int ex = block_excl_scan(v, nullptr) + boff[blockIdx.x];
  if (i < n) { row_ptr[i] = ex; cursor[i] = ex; }
  if (i == n - 1) row_ptr[n] = ex + v;
}

__global__ __launch_bounds__(256) void k_fill(const int* __restrict__ ei, int E, int n,
                                              int* cursor, int* __restrict__ srcs) {
  int i = blockIdx.x * 256 + threadIdx.x;
  if (i >= E + n) return;
  int s, d;
  if (i < E) { s = ei[i]; d = ei[E + i]; }
  else       { s = i - E; d = s; }
  int slot = atomicAdd(&cursor[d], 1);
  srcs[slot] = s;
}

// ---------------- fp32 -> split-bf16 planes (x input) ----------------
__global__ __launch_bounds__(256) void k_cvt(const float* __restrict__ x,
                                             unsigned short* __restrict__ hi,
                                             unsigned short* __restrict__ lo, int n4) {
  int i = blockIdx.x * 256 + threadIdx.x;
  if (i >= n4) return;
  float4 v = ((const float4*)x)[i];
  ushort4 h, l;
  h.x = f2bf(v.x); l.x = f2bf(v.x - bf2f(h.x));
  h.y = f2bf(v.y); l.y = f2bf(v.y - bf2f(h.y));
  h.z = f2bf(v.z); l.z = f2bf(v.z - bf2f(h.z));
  h.w = f2bf(v.w); l.w = f2bf(v.w - bf2f(h.w));
  ((ushort4*)hi)[i] = h;
  ((ushort4*)lo)[i] = l;
}

// ---------------------------------------------------------------------------
// Weight prep, fully parallel. Swizzled storage for element (n, k):
//   nt=n/16, lr=n%16, j=k/32, kb=(k%32)/8, e=k%8
//   off = ((j*9+nt)*64 + kb*16+lr)*8 + e     (B-frag load = contiguous 1KB)
// blocks 0..63  : transpose/split W[k][n] -> nt 0..7   (1 elem/thread,
//                 coalesced row-major reads of W)
// blocks 64..95 : projection cols n=128+hh (src), n=128+H+hh (dst); one wave
//                 per k-row; lanes hold 2 elems; segmented shfl_xor reduce.
// ---------------------------------------------------------------------------
__global__ __launch_bounds__(256) void k_cvt_w(const float* __restrict__ W,
                                               const float* __restrict__ a_s,
                                               const float* __restrict__ a_d,
                                               unsigned short* __restrict__ hi2,
                                               unsigned short* __restrict__ lo2, int H) {
  int b = blockIdx.x;
  if (b < 64) {
    int i = b * 256 + threadIdx.x;       // 16384 threads, one W element each
    int k = i >> 7, n = i & 127;
    float v = W[i];                      // coalesced
    unsigned short hh = f2bf(v), ll = f2bf(v - bf2f(hh));
    int nt = n >> 4, lr = n & 15;
    int j = k >> 5, kb = (k >> 3) & 3, e = k & 7;
    int off = ((j * 9 + nt) * 64 + kb * 16 + lr) * 8 + e;
    hi2[off] = hh; lo2[off] = ll;
    return;
  }
  if (H <= 0) return;
  // projection columns: wave w handles k = w
  int w = (b - 64) * 4 + (threadIdx.x >> 6);   // 0..127
  int lane = threadIdx.x & 63;
  int c0 = lane * 2;
  float2 wv = *(const float2*)(W + w * 128 + c0);
  float2 as2 = *(const float2*)(a_s + c0);     // [H][C] flat == aligned with row
  float2 ad2 = *(const float2*)(a_d + c0);
  float ps = wv.x * as2.x + wv.y * as2.y;
  float pd = wv.x * ad2.x + wv.y * ad2.y;
  int C = 128 / H;
  int CL = C >> 1;                             // lanes per head segment
  for (int off = 1; off < CL; off <<= 1) {
    ps += __shfl_xor(ps, off);
    pd += __shfl_xor(pd, off);
  }
  if ((lane & (CL - 1)) == 0) {
    int hh = lane / CL;                        // head index
    int j = w >> 5, kb = (w >> 3) & 3, e = w & 7;
    int base = ((j * 9 + 8) * 64 + kb * 16) * 8 + e;   // nt=8, lr=0
    unsigned short hsv = f2bf(ps), lsv = f2bf(ps - bf2f(hsv));
    unsigned short hdv = f2bf(pd), ldv = f2bf(pd - bf2f(hdv));
    hi2[base + hh * 8] = hsv;       lo2[base + hh * 8] = lsv;        // n=128+hh
    hi2[base + (H + hh) * 8] = hdv; lo2[base + (H + hh) * 8] = ldv;  // n=128+H+hh
  }
}

// ---------------------------------------------------------------------------
// C[M,128] = A[M,128] @ W (+bias,+relu), als/ald from ext tile nt=8.
// Split-bf16 MFMA, no LDS, no barriers. 4 waves x 16 rows = 64 rows/block.
// mfma_f32_16x16x32_bf16: A[lane&15][(lane>>4)*8+i], B[(lane>>4)*8+i][lane&15],
// C col=lane&15, row=(lane>>4)*4+reg (m89-verified layout).
// ---------------------------------------------------------------------------
__global__ __launch_bounds__(256) void k_gemm_bf(const unsigned short* __restrict__ Ahi,
                                                 const unsigned short* __restrict__ Alo,
                                                 const unsigned short* __restrict__ hi2,
                                                 const unsigned short* __restrict__ lo2,
                                                 const float* __restrict__ bias,
                                                 float* __restrict__ C,
                                                 float* __restrict__ als,
                                                 float* __restrict__ ald,
                                                 int M, int H, int relu) {
  int tid = threadIdx.x;
  int lane = tid & 63;
  int wv = tid >> 6;
  int m0 = blockIdx.x * 64 + wv * 16;
  int lr = lane & 15;
  int kb = lane >> 4;
  int arow = m0 + lr; if (arow >= M) arow = M - 1;
  const size_t abase = (size_t)arow * 128;

  short8 ahi[4], alo[4];
  #pragma unroll
  for (int j = 0; j < 4; j++) {
    int k0 = j * 32 + kb * 8;
    ahi[j] = *(const short8*)(Ahi + abase + k0);
    alo[j] = *(const short8*)(Alo + abase + k0);
  }

  floatx4 acc[9];
  #pragma unroll
  for (int nt = 0; nt < 9; nt++) acc[nt] = (floatx4){0.f, 0.f, 0.f, 0.f};

  #pragma unroll
  for (int j = 0; j < 4; j++) {
    #pragma unroll
    for (int nt = 0; nt < 9; nt++) {
      int boff = ((j * 9 + nt) * 64 + lane) * 8;
      short8 bhi = *(const short8*)(hi2 + boff);
      short8 blo = *(const short8*)(lo2 + boff);
      acc[nt] = __builtin_amdgcn_mfma_f32_16x16x32_bf16(ahi[j], bhi, acc[nt], 0, 0, 0);
      acc[nt] = __builtin_amdgcn_mfma_f32_16x16x32_bf16(ahi[j], blo, acc[nt], 0, 0, 0);
      acc[nt] = __builtin_amdgcn_mfma_f32_16x16x32_bf16(alo[j], bhi, acc[nt], 0, 0, 0);
    }
  }

  #pragma unroll
  for (int nt = 0; nt < 8; nt++) {
    int col = nt * 16 + lr;
    #pragma unroll
    for (int r = 0; r < 4; r++) {
      int row = m0 + kb * 4 + r;
      if (row < M) {
        float v = acc[nt][r];
        if (bias) v += bias[col];
        if (relu) v = fmaxf(v, 0.f);
        C[(size_t)row * 128 + col] = v;
      }
    }
  }
  if (als) {
    #pragma unroll
    for (int r = 0; r < 4; r++) {
      int row = m0 + kb * 4 + r;
      if (row < M) {
        float v = acc[8][r];
        if (H == 8) {
          if (lr < 8) als[row * 8 + lr] = v;
          else        ald[row * 8 + (lr - 8)] = v;
        } else {
          if (lr == 0) als[row] = v;
          else if (lr == 1) ald[row] = v;
        }
      }
    }
  }
}

// ---------------------------------------------------------------------------
// Fused per-node softmax + aggregation, v2. One wave per destination node.
// pass 1: per-(edge,head) logits e -> LDS (deg<=128), online (m,d) reduce.
// pass 1.5: LDS e -> alpha in place (exp computed ONCE per (edge,head)).
// pass 2: per edge, all 64 lanes gather the 512B h row (float2/lane),
//         alpha via LDS broadcast; no cross-lane reduce at the end.
// deg>128 tail: recompute path (statistically never for Poisson(17)).
// ---------------------------------------------------------------------------
template <int H>
__global__ __launch_bounds__(256) void k_agg(const int* __restrict__ row_ptr,
                                             const int* __restrict__ srcs,
                                             const float* __restrict__ als,
                                             const float* __restrict__ ald,
                                             const float* __restrict__ h,
                                             const float* __restrict__ bias,
                                             unsigned short* __restrict__ outHi,
                                             unsigned short* __restrict__ outLo, int n) {
  __shared__ float eL[4][128 * H];
  __shared__ int svL[4][128];
  const int EPP = 64 / H;
  int lane = threadIdx.x & 63;
  int wv = threadIdx.x >> 6;
  int v = blockIdx.x * 4 + wv;
  bool active = (v < n);
  int s0 = 0, s1 = 0;
  int eo = lane / H;
  int hd = lane % H;
  float ed = 0.f;
  if (active) { s0 = row_ptr[v]; s1 = row_ptr[v + 1]; ed = ald[v * H + hd]; }
  // pass 1: logits -> LDS, online (m,d)
  float m = -1e30f, d = 0.f;
  for (int j = s0 + eo; j < s1; j += EPP) {
    int sv = srcs[j];
    float e = als[sv * H + hd] + ed;
    e = (e > 0.f) ? e : 0.2f * e;
    int idx = j - s0;
    if (idx < 128) {
      eL[wv][idx * H + hd] = e;
      if (hd == 0) svL[wv][idx] = sv;
    }
    float nm = fmaxf(m, e);
    d = d * __expf(m - nm) + __expf(e - nm);
    m = nm;
  }
  #pragma unroll
  for (int off = H; off < 64; off <<= 1) {
    float om = __shfl_xor(m, off);
    float od = __shfl_xor(d, off);
    float nm = fmaxf(m, om);
    d = d * __expf(m - nm) + od * __expf(om - nm);
    m = nm;
  }
  float inv = 1.f / d;  // d >= 1 (self loop)
  // pass 1.5: e -> alpha in place (t % H == hd since H divides 64)
  int nE = min(s1 - s0, 128);
  for (int t = lane; t < nE * H; t += 64)
    eL[wv][t] = __expf(eL[wv][t] - m) * inv;
  // pass 2: uniform-row aggregation; lane owns channels c, c+1
  int c = lane * 2;
  int hd2 = (H == 8) ? (lane >> 3) : 0;
  float m2 = __shfl(m, hd2), inv2 = __shfl(inv, hd2), ed2 = __shfl(ed, hd2);
  float a0 = 0.f, a1 = 0.f;
  for (int jj = 0; jj < nE; ++jj) {
    int sv = svL[wv][jj];
    float al = eL[wv][jj * H + hd2];
    float2 hv = *(const float2*)(h + (size_t)sv * 128 + c);
    a0 += al * hv.x; a1 += al * hv.y;
  }
  for (int j = s0 + 128; j < s1; ++j) {  // rare tail
    int sv = srcs[j];
    float e = als[sv * H + hd2] + ed2;
    e = (e > 0.f) ? e : 0.2f * e;
    float al = __expf(e - m2) * inv2;
    float2 hv = *(const float2*)(h + (size_t)sv * 128 + c);
    a0 += al * hv.x; a1 += al * hv.y;
  }
  if (active) {
    a0 = fmaxf(a0 + bias[c], 0.f);
    a1 = fmaxf(a1 + bias[c + 1], 0.f);
    ushort2 h2, l2;
    h2.x = f2bf(a0); l2.x = f2bf(a0 - bf2f(h2.x));
    h2.y = f2bf(a1); l2.y = f2bf(a1 - bf2f(h2.y));
    *(ushort2*)(outHi + (size_t)v * 128 + c) = h2;
    *(ushort2*)(outLo + (size_t)v * 128 + c) = l2;
  }
}

extern "C" void kernel_launch(void* const* d_in, const int* in_sizes, int n_in,
                              void* d_out, int out_size, void* d_ws, size_t ws_size,
                              hipStream_t stream) {
  const float* x  = (const float*)d_in[0];
  const int*   ei = (const int*)d_in[1];
  const int N  = in_sizes[0] / 128;
  const int E  = in_sizes[1] / 2;
  const int ET = E + N;
  const int NB = (N + 255) / 256;

  const float *Wl[5], *as[5], *ad[5], *bl[5];
  for (int l = 0; l < 5; l++) {
    Wl[l] = (const float*)d_in[3 + 4 * l];
    as[l] = (const float*)d_in[4 + 4 * l];
    ad[l] = (const float*)d_in[5 + 4 * l];
    bl[l] = (const float*)d_in[6 + 4 * l];
  }
  const float* W_lin = (const float*)d_in[23];
  const float* b_lin = (const float*)d_in[24];

  char* p = (char*)d_ws;
  auto alloc = [&](size_t bytes) { void* r = (void*)p; p += (bytes + 255) & ~size_t(255); return r; };
  float* h    = (float*)alloc((size_t)N * 128 * 4);
  unsigned short* pAhi = (unsigned short*)alloc((size_t)N * 128 * 2);
  unsigned short* pAlo = (unsigned short*)alloc((size_t)N * 128 * 2);
  unsigned short* pBhi = (unsigned short*)alloc((size_t)N * 128 * 2);
  unsigned short* pBlo = (unsigned short*)alloc((size_t)N * 128 * 2);
  unsigned short* WtHi = (unsigned short*)alloc(144 * 128 * 2);
  unsigned short* WtLo = (unsigned short*)alloc(144 * 128 * 2);
  float* als  = (float*)alloc((size_t)N * 8 * 4);
  float* ald  = (float*)alloc((size_t)N * 8 * 4);
  int* row_ptr = (int*)alloc((size_t)(N + 1) * 4);
  int* cursor  = (int*)alloc((size_t)N * 4);
  int* deg     = (int*)alloc((size_t)N * 4);
  int* srcs    = (int*)alloc((size_t)ET * 4);
  int* bsum    = (int*)alloc((size_t)NB * 4);
  int* boff    = (int*)alloc((size_t)NB * 4);
  (void)ws_size; (void)n_in; (void)out_size;

  dim3 b256(256);
  // CSR build (once; reused across all 5 layers)
  k_deg_init<<<NB, b256, 0, stream>>>(deg, N);
  k_count<<<(E + 255) / 256, b256, 0, stream>>>(ei, E, deg);
  k_bsum<<<NB, b256, 0, stream>>>(deg, bsum, N);
  k_bscan<<<1, b256, 0, stream>>>(bsum, boff, NB);
  k_rowptr<<<NB, b256, 0, stream>>>(deg, boff, row_ptr, cursor, N);
  k_fill<<<(ET + 255) / 256, b256, 0, stream>>>(ei, E, N, cursor, srcs);

  // x -> split-bf16 planes
  int n4 = N * 128 / 4;
  k_cvt<<<(n4 + 255) / 256, b256, 0, stream>>>(x, pAhi, pAlo, n4);

  int gemm_grid = (N + 63) / 64;
  unsigned short *inHi = pAhi, *inLo = pAlo, *outHi = pBhi, *outLo = pBlo;
  for (int l = 0; l < 5; l++) {
    int H = (l < 4) ? 8 : 1;
    k_cvt_w<<<96, b256, 0, stream>>>(Wl[l], as[l], ad[l], WtHi, WtLo, H);
    k_gemm_bf<<<gemm_grid, b256, 0, stream>>>(inHi, inLo, WtHi, WtLo, nullptr,
                                              h, als, ald, N, H, 0);
    if (l < 4)
      k_agg<8><<<(N + 3) / 4, b256, 0, stream>>>(row_ptr, srcs, als, ald, h, bl[l], outHi, outLo, N);
    else
      k_agg<1><<<(N + 3) / 4, b256, 0, stream>>>(row_ptr, srcs, als, ald, h, bl[l], outHi, outLo, N);
    unsigned short* t;
    t = inHi; inHi = outHi; outHi = t;
    t = inLo; inLo = outLo; outLo = t;
  }
  k_cvt_w<<<96, b256, 0, stream>>>(W_lin, nullptr, nullptr, WtHi, WtLo, 0);
  k_gemm_bf<<<gemm_grid, b256, 0, stream>>>(inHi, inLo, WtHi, WtLo, b_lin,
                                            (float*)d_out, nullptr, nullptr, N, 0, 1);
}

// Round 9
// 699.094 us; speedup vs baseline: 1.2441x; 1.0269x over previous
//
#include <hip/hip_runtime.h>

// ---------------------------------------------------------------------------
// GAT (5 layers, 8 heads / last 1 head) + final linear.
// - GEMM: split-bf16 (hi+lo) MFMA, fp32 accumulate. Wt extended to 144 cols
//   [W | W@Ms | W@Md] (logits fused as GEMM outputs), stored fragment-
//   contiguous by k_cvt_w; k_gemm stages it into LDS (2 K-phases, pure
//   16B-chunk copy) so the MFMA loop reads LDS only.
// - k_agg: LDS-cached alpha (exp once), pass 2 gathers 2 edge-rows x float4
//   with 2x unroll -> 4 rows in flight.
// ---------------------------------------------------------------------------

typedef short short8 __attribute__((ext_vector_type(8)));
typedef float floatx4 __attribute__((ext_vector_type(4)));

__device__ __forceinline__ unsigned short f2bf(float f) {
  unsigned u = __float_as_uint(f);
  return (unsigned short)((u + 0x7FFF + ((u >> 16) & 1)) >> 16);  // RNE
}
__device__ __forceinline__ float bf2f(unsigned short h) {
  return __uint_as_float(((unsigned)h) << 16);
}

// ---------------- CSR build ----------------
__global__ __launch_bounds__(256) void k_deg_init(int* deg, int n) {
  int i = blockIdx.x * 256 + threadIdx.x;
  if (i < n) deg[i] = 1;  // self loop
}

__global__ __launch_bounds__(256) void k_count(const int* __restrict__ ei, int E, int* deg) {
  int i = blockIdx.x * 256 + threadIdx.x;
  if (i < E) atomicAdd(&deg[ei[E + i]], 1);
}

__device__ __forceinline__ int block_excl_scan(int v, int* tot) {
  __shared__ int wsum[4];
  int lane = threadIdx.x & 63, w = threadIdx.x >> 6;
  int x = v;
  #pragma unroll
  for (int off = 1; off < 64; off <<= 1) {
    int y = __shfl_up(x, off);
    if (lane >= off) x += y;
  }
  if (lane == 63) wsum[w] = x;
  __syncthreads();
  int wbase = 0;
  #pragma unroll
  for (int i = 0; i < 4; i++) wbase += (i < w) ? wsum[i] : 0;
  if (tot) *tot = wsum[0] + wsum[1] + wsum[2] + wsum[3];
  return wbase + x - v;
}

__global__ __launch_bounds__(256) void k_bsum(const int* __restrict__ deg, int* __restrict__ bsum, int n) {
  int i = blockIdx.x * 256 + threadIdx.x;
  int v = (i < n) ? deg[i] : 0;
  int tot;
  block_excl_scan(v, &tot);
  if (threadIdx.x == 0) bsum[blockIdx.x] = tot;
}

__global__ __launch_bounds__(256) void k_bscan(const int* __restrict__ bsum, int* __restrict__ boff, int nb) {
  int t = threadIdx.x;
  int v = (t < nb) ? bsum[t] : 0;
  int ex = block_excl_scan(v, nullptr);
  if (t < nb) boff[t] = ex;
}

__global__ __launch_bounds__(256) void k_rowptr(const int* __restrict__ deg,
                                                const int* __restrict__ boff,
                                                int* __restrict__ row_ptr,
                                                int* __restrict__ cursor, int n) {
  int i = blockIdx.x * 256 + threadIdx.x;
  int v = (i < n) ? deg[i] : 0;
  int ex = block_excl_scan(v, nullptr) + boff[blockIdx.x];
  if (i < n) { row_ptr[i] = ex; cursor[i] = ex; }
  if (i == n - 1) row_ptr[n] = ex + v;
}

__global__ __launch_bounds__(256) void k_fill(const int* __restrict__ ei, int E, int n,
                                              int* cursor, int* __restrict__ srcs) {
  int i = blockIdx.x * 256 + threadIdx.x;
  if (i >= E + n) return;
  int s, d;
  if (i < E) { s = ei[i]; d = ei[E + i]; }
  else       { s = i - E; d = s; }
  int slot = atomicAdd(&cursor[d], 1);
  srcs[slot] = s;
}

// ---------------- fp32 -> split-bf16 planes (x input) ----------------
__global__ __launch_bounds__(256) void k_cvt(const float* __restrict__ x,
                                             unsigned short* __restrict__ hi,
                                             unsigned short* __restrict__ lo, int n4) {
  int i = blockIdx.x * 256 + threadIdx.x;
  if (i >= n4) return;
  float4 v = ((const float4*)x)[i];
  ushort4 h, l;
  h.x = f2bf(v.x); l.x = f2bf(v.x - bf2f(h.x));
  h.y = f2bf(v.y); l.y = f2bf(v.y - bf2f(h.y));
  h.z = f2bf(v.z); l.z = f2bf(v.z - bf2f(h.z));
  h.w = f2bf(v.w); l.w = f2bf(v.w - bf2f(h.w));
  ((ushort4*)hi)[i] = h;
  ((ushort4*)lo)[i] = l;
}

// ---------------------------------------------------------------------------
// Weight prep, fully parallel. Swizzled storage for element (n, k):
//   nt=n/16, lr=n%16, j=k/32, kb=(k%32)/8, e=k%8
//   off = ((j*9+nt)*64 + kb*16+lr)*8 + e     (B-frag = contiguous 1KB)
// blocks 0..63  : transpose/split W (1 elem/thread, coalesced reads)
// blocks 64..95 : projection cols (one wave per k-row, segmented shfl reduce)
// ---------------------------------------------------------------------------
__global__ __launch_bounds__(256) void k_cvt_w(const float* __restrict__ W,
                                               const float* __restrict__ a_s,
                                               const float* __restrict__ a_d,
                                               unsigned short* __restrict__ hi2,
                                               unsigned short* __restrict__ lo2, int H) {
  int b = blockIdx.x;
  if (b < 64) {
    int i = b * 256 + threadIdx.x;       // 16384 threads, one W element each
    int k = i >> 7, n = i & 127;
    float v = W[i];                      // coalesced
    unsigned short hh = f2bf(v), ll = f2bf(v - bf2f(hh));
    int nt = n >> 4, lr = n & 15;
    int j = k >> 5, kb = (k >> 3) & 3, e = k & 7;
    int off = ((j * 9 + nt) * 64 + kb * 16 + lr) * 8 + e;
    hi2[off] = hh; lo2[off] = ll;
    return;
  }
  if (H <= 0) return;
  // projection columns: wave w handles k = w
  int w = (b - 64) * 4 + (threadIdx.x >> 6);   // 0..127
  int lane = threadIdx.x & 63;
  int c0 = lane * 2;
  float2 wv = *(const float2*)(W + w * 128 + c0);
  float2 as2 = *(const float2*)(a_s + c0);
  float2 ad2 = *(const float2*)(a_d + c0);
  float ps = wv.x * as2.x + wv.y * as2.y;
  float pd = wv.x * ad2.x + wv.y * ad2.y;
  int C = 128 / H;
  int CL = C >> 1;                             // lanes per head segment
  for (int off = 1; off < CL; off <<= 1) {
    ps += __shfl_xor(ps, off);
    pd += __shfl_xor(pd, off);
  }
  if ((lane & (CL - 1)) == 0) {
    int hh = lane / CL;                        // head index
    int j = w >> 5, kb = (w >> 3) & 3, e = w & 7;
    int base = ((j * 9 + 8) * 64 + kb * 16) * 8 + e;   // nt=8, lr=0
    unsigned short hsv = f2bf(ps), lsv = f2bf(ps - bf2f(hsv));
    unsigned short hdv = f2bf(pd), ldv = f2bf(pd - bf2f(hdv));
    hi2[base + hh * 8] = hsv;       lo2[base + hh * 8] = lsv;
    hi2[base + (H + hh) * 8] = hdv; lo2[base + (H + hh) * 8] = ldv;
  }
}

// ---------------------------------------------------------------------------
// C[M,128] = A[M,128] @ W (+bias,+relu), als/ald from ext tile nt=8.
// Wt staged into LDS in 2 K-phases (18.4KB x 2 planes = 36.9 KB); MFMA loop
// reads LDS only (contiguous per-lane 16B ds_read_b128, conflict-free).
// mfma_f32_16x16x32_bf16: A[lane&15][(lane>>4)*8+i], B[(lane>>4)*8+i][lane&15],
// C col=lane&15, row=(lane>>4)*4+reg (m89-verified layout).
// ---------------------------------------------------------------------------
__global__ __launch_bounds__(256) void k_gemm_bf(const unsigned short* __restrict__ Ahi,
                                                 const unsigned short* __restrict__ Alo,
                                                 const unsigned short* __restrict__ hi2,
                                                 const unsigned short* __restrict__ lo2,
                                                 const float* __restrict__ bias,
                                                 float* __restrict__ C,
                                                 float* __restrict__ als,
                                                 float* __restrict__ ald,
                                                 int M, int H, int relu) {
  __shared__ unsigned short lHi[9216];   // j-half x 9 nt x 64 lanes x 8 shorts
  __shared__ unsigned short lLo[9216];
  int tid = threadIdx.x;
  int lane = tid & 63;
  int wv = tid >> 6;
  int m0 = blockIdx.x * 64 + wv * 16;
  int lr = lane & 15;
  int kb = lane >> 4;
  int arow = m0 + lr; if (arow >= M) arow = M - 1;   // clamp (stores guarded)
  const size_t abase = (size_t)arow * 128;

  short8 ahi[4], alo[4];
  #pragma unroll
  for (int j = 0; j < 4; j++) {
    int k0 = j * 32 + kb * 8;
    ahi[j] = *(const short8*)(Ahi + abase + k0);
    alo[j] = *(const short8*)(Alo + abase + k0);
  }

  floatx4 acc[9];
  #pragma unroll
  for (int nt = 0; nt < 9; nt++) acc[nt] = (floatx4){0.f, 0.f, 0.f, 0.f};

  #pragma unroll
  for (int p = 0; p < 2; p++) {
    if (p) __syncthreads();             // all waves done reading phase 0
    for (int ci = tid; ci < 1152; ci += 256) {   // stage 18.4KB x2 planes
      ((short8*)lHi)[ci] = ((const short8*)(hi2 + p * 9216))[ci];
      ((short8*)lLo)[ci] = ((const short8*)(lo2 + p * 9216))[ci];
    }
    __syncthreads();
    #pragma unroll
    for (int jj = 0; jj < 2; jj++) {
      int j = p * 2 + jj;
      #pragma unroll
      for (int nt = 0; nt < 9; nt++) {
        int boff = ((jj * 9 + nt) * 64 + lane) * 8;
        short8 bhi = *(const short8*)(lHi + boff);
        short8 blo = *(const short8*)(lLo + boff);
        acc[nt] = __builtin_amdgcn_mfma_f32_16x16x32_bf16(ahi[j], bhi, acc[nt], 0, 0, 0);
        acc[nt] = __builtin_amdgcn_mfma_f32_16x16x32_bf16(ahi[j], blo, acc[nt], 0, 0, 0);
        acc[nt] = __builtin_amdgcn_mfma_f32_16x16x32_bf16(alo[j], bhi, acc[nt], 0, 0, 0);
      }
    }
  }

  #pragma unroll
  for (int nt = 0; nt < 8; nt++) {
    int col = nt * 16 + lr;
    #pragma unroll
    for (int r = 0; r < 4; r++) {
      int row = m0 + kb * 4 + r;
      if (row < M) {
        float v = acc[nt][r];
        if (bias) v += bias[col];
        if (relu) v = fmaxf(v, 0.f);
        C[(size_t)row * 128 + col] = v;
      }
    }
  }
  if (als) {
    #pragma unroll
    for (int r = 0; r < 4; r++) {
      int row = m0 + kb * 4 + r;
      if (row < M) {
        float v = acc[8][r];
        if (H == 8) {
          if (lr < 8) als[row * 8 + lr] = v;
          else        ald[row * 8 + (lr - 8)] = v;
        } else {
          if (lr == 0) als[row] = v;
          else if (lr == 1) ald[row] = v;
        }
      }
    }
  }
}

// ---------------------------------------------------------------------------
// Fused per-node softmax + aggregation. One wave per destination node.
// pass 1: per-(edge,head) logits -> LDS (deg<=128), online (m,d) reduce.
// pass 1.5: LDS e -> alpha in place (exp once per (edge,head)).
// pass 2: 2 edge slots x 32 lanes x float4, 2x unrolled -> 4 rows in flight;
//         alpha via LDS broadcast; slot-merge via shfl_xor(32).
// ---------------------------------------------------------------------------
template <int H>
__global__ __launch_bounds__(256) void k_agg(const int* __restrict__ row_ptr,
                                             const int* __restrict__ srcs,
                                             const float* __restrict__ als,
                                             const float* __restrict__ ald,
                                             const float* __restrict__ h,
                                             const float* __restrict__ bias,
                                             unsigned short* __restrict__ outHi,
                                             unsigned short* __restrict__ outLo, int n) {
  __shared__ float eL[4][128 * H];
  __shared__ int svL[4][128];
  const int EPP = 64 / H;
  int lane = threadIdx.x & 63;
  int wv = threadIdx.x >> 6;
  int v = blockIdx.x * 4 + wv;
  bool active = (v < n);
  int s0 = 0, s1 = 0;
  int eo = lane / H;
  int hd = lane % H;
  float ed = 0.f;
  if (active) { s0 = row_ptr[v]; s1 = row_ptr[v + 1]; ed = ald[v * H + hd]; }
  // pass 1: logits -> LDS, online (m,d)
  float m = -1e30f, d = 0.f;
  for (int j = s0 + eo; j < s1; j += EPP) {
    int sv = srcs[j];
    float e = als[sv * H + hd] + ed;
    e = (e > 0.f) ? e : 0.2f * e;
    int idx = j - s0;
    if (idx < 128) {
      eL[wv][idx * H + hd] = e;
      if (hd == 0) svL[wv][idx] = sv;
    }
    float nm = fmaxf(m, e);
    d = d * __expf(m - nm) + __expf(e - nm);
    m = nm;
  }
  #pragma unroll
  for (int off = H; off < 64; off <<= 1) {
    float om = __shfl_xor(m, off);
    float od = __shfl_xor(d, off);
    float nm = fmaxf(m, om);
    d = d * __expf(m - nm) + od * __expf(om - nm);
    m = nm;
  }
  float inv = 1.f / d;  // d >= 1 (self loop)
  // pass 1.5: e -> alpha in place (t % H == hd since H divides 64)
  int nE = min(s1 - s0, 128);
  for (int t = lane; t < nE * H; t += 64)
    eL[wv][t] = __expf(eL[wv][t] - m) * inv;
  // pass 2: 2 slots x float4; 2x unroll -> 4 rows in flight
  int slot = lane >> 5;
  int l5 = lane & 31;
  int c0 = l5 * 4;
  int hd2 = (H == 8) ? (l5 >> 2) : 0;
  float m2 = __shfl(m, hd2), inv2 = __shfl(inv, hd2), ed2 = __shfl(ed, hd2);
  float ax = 0.f, ay = 0.f, az = 0.f, aw = 0.f;
  int jj = slot;
  for (; jj + 2 < nE; jj += 4) {
    int sv0 = svL[wv][jj], sv1 = svL[wv][jj + 2];
    float al0 = eL[wv][jj * H + hd2], al1 = eL[wv][(jj + 2) * H + hd2];
    float4 h0 = *(const float4*)(h + (size_t)sv0 * 128 + c0);
    float4 h1 = *(const float4*)(h + (size_t)sv1 * 128 + c0);
    ax += al0 * h0.x + al1 * h1.x;
    ay += al0 * h0.y + al1 * h1.y;
    az += al0 * h0.z + al1 * h1.z;
    aw += al0 * h0.w + al1 * h1.w;
  }
  for (; jj < nE; jj += 2) {
    int sv0 = svL[wv][jj];
    float al0 = eL[wv][jj * H + hd2];
    float4 h0 = *(const float4*)(h + (size_t)sv0 * 128 + c0);
    ax += al0 * h0.x; ay += al0 * h0.y; az += al0 * h0.z; aw += al0 * h0.w;
  }
  for (int j = s0 + 128 + slot; j < s1; j += 2) {  // rare tail (deg>128)
    int sv = srcs[j];
    float e = als[sv * H + hd2] + ed2;
    e = (e > 0.f) ? e : 0.2f * e;
    float al = __expf(e - m2) * inv2;
    float4 hv = *(const float4*)(h + (size_t)sv * 128 + c0);
    ax += al * hv.x; ay += al * hv.y; az += al * hv.z; aw += al * hv.w;
  }
  ax += __shfl_xor(ax, 32);
  ay += __shfl_xor(ay, 32);
  az += __shfl_xor(az, 32);
  aw += __shfl_xor(aw, 32);
  if (active && slot == 0) {
    float o[4];
    o[0] = fmaxf(ax + bias[c0 + 0], 0.f);
    o[1] = fmaxf(ay + bias[c0 + 1], 0.f);
    o[2] = fmaxf(az + bias[c0 + 2], 0.f);
    o[3] = fmaxf(aw + bias[c0 + 3], 0.f);
    ushort4 h4, l4;
    h4.x = f2bf(o[0]); l4.x = f2bf(o[0] - bf2f(h4.x));
    h4.y = f2bf(o[1]); l4.y = f2bf(o[1] - bf2f(h4.y));
    h4.z = f2bf(o[2]); l4.z = f2bf(o[2] - bf2f(h4.z));
    h4.w = f2bf(o[3]); l4.w = f2bf(o[3] - bf2f(h4.w));
    *(ushort4*)(outHi + (size_t)v * 128 + c0) = h4;
    *(ushort4*)(outLo + (size_t)v * 128 + c0) = l4;
  }
}

extern "C" void kernel_launch(void* const* d_in, const int* in_sizes, int n_in,
                              void* d_out, int out_size, void* d_ws, size_t ws_size,
                              hipStream_t stream) {
  const float* x  = (const float*)d_in[0];
  const int*   ei = (const int*)d_in[1];
  const int N  = in_sizes[0] / 128;
  const int E  = in_sizes[1] / 2;
  const int ET = E + N;
  const int NB = (N + 255) / 256;

  const float *Wl[5], *as[5], *ad[5], *bl[5];
  for (int l = 0; l < 5; l++) {
    Wl[l] = (const float*)d_in[3 + 4 * l];
    as[l] = (const float*)d_in[4 + 4 * l];
    ad[l] = (const float*)d_in[5 + 4 * l];
    bl[l] = (const float*)d_in[6 + 4 * l];
  }
  const float* W_lin = (const float*)d_in[23];
  const float* b_lin = (const float*)d_in[24];

  char* p = (char*)d_ws;
  auto alloc = [&](size_t bytes) { void* r = (void*)p; p += (bytes + 255) & ~size_t(255); return r; };
  float* h    = (float*)alloc((size_t)N * 128 * 4);
  unsigned short* pAhi = (unsigned short*)alloc((size_t)N * 128 * 2);
  unsigned short* pAlo = (unsigned short*)alloc((size_t)N * 128 * 2);
  unsigned short* pBhi = (unsigned short*)alloc((size_t)N * 128 * 2);
  unsigned short* pBlo = (unsigned short*)alloc((size_t)N * 128 * 2);
  unsigned short* WtHi = (unsigned short*)alloc(144 * 128 * 2);
  unsigned short* WtLo = (unsigned short*)alloc(144 * 128 * 2);
  float* als  = (float*)alloc((size_t)N * 8 * 4);
  float* ald  = (float*)alloc((size_t)N * 8 * 4);
  int* row_ptr = (int*)alloc((size_t)(N + 1) * 4);
  int* cursor  = (int*)alloc((size_t)N * 4);
  int* deg     = (int*)alloc((size_t)N * 4);
  int* srcs    = (int*)alloc((size_t)ET * 4);
  int* bsum    = (int*)alloc((size_t)NB * 4);
  int* boff    = (int*)alloc((size_t)NB * 4);
  (void)ws_size; (void)n_in; (void)out_size;

  dim3 b256(256);
  // CSR build (once; reused across all 5 layers)
  k_deg_init<<<NB, b256, 0, stream>>>(deg, N);
  k_count<<<(E + 255) / 256, b256, 0, stream>>>(ei, E, deg);
  k_bsum<<<NB, b256, 0, stream>>>(deg, bsum, N);
  k_bscan<<<1, b256, 0, stream>>>(bsum, boff, NB);
  k_rowptr<<<NB, b256, 0, stream>>>(deg, boff, row_ptr, cursor, N);
  k_fill<<<(ET + 255) / 256, b256, 0, stream>>>(ei, E, N, cursor, srcs);

  // x -> split-bf16 planes
  int n4 = N * 128 / 4;
  k_cvt<<<(n4 + 255) / 256, b256, 0, stream>>>(x, pAhi, pAlo, n4);

  int gemm_grid = (N + 63) / 64;
  unsigned short *inHi = pAhi, *inLo = pAlo, *outHi = pBhi, *outLo = pBlo;
  for (int l = 0; l < 5; l++) {
    int H = (l < 4) ? 8 : 1;
    k_cvt_w<<<96, b256, 0, stream>>>(Wl[l], as[l], ad[l], WtHi, WtLo, H);
    k_gemm_bf<<<gemm_grid, b256, 0, stream>>>(inHi, inLo, WtHi, WtLo, nullptr,
                                              h, als, ald, N, H, 0);
    if (l < 4)
      k_agg<8><<<(N + 3) / 4, b256, 0, stream>>>(row_ptr, srcs, als, ald, h, bl[l], outHi, outLo, N);
    else
      k_agg<1><<<(N + 3) / 4, b256, 0, stream>>>(row_ptr, srcs, als, ald, h, bl[l], outHi, outLo, N);
    unsigned short* t;
    t = inHi; inHi = outHi; outHi = t;
    t = inLo; inLo = outLo; outLo = t;
  }
  k_cvt_w<<<96, b256, 0, stream>>>(W_lin, nullptr, nullptr, WtHi, WtLo, 0);
  k_gemm_bf<<<gemm_grid, b256, 0, stream>>>(inHi, inLo, WtHi, WtLo, b_lin,
                                            (float*)d_out, nullptr, nullptr, N, 0, 1);
}

// Round 10
// 670.413 us; speedup vs baseline: 1.2973x; 1.0428x over previous
//
#include <hip/hip_runtime.h>

// ---------------------------------------------------------------------------
// GAT (5 layers, 8 heads / last 1 head) + final linear.
// - GEMM: split-bf16 (hi+lo) MFMA, fp32 accumulate. Wt extended to 144 cols
//   [W | W@Ms | W@Md] (logits fused as GEMM outputs), fragment-contiguous,
//   ALL 6 layers converted in ONE upfront kernel; gemm stages Wt via LDS.
// - k_agg: LDS-cached alpha (exp once); pass 2 = 4 edge-slots x 16 lanes x
//   32B/lane, 2x unrolled -> 8 rows in flight.
// ---------------------------------------------------------------------------

typedef short short8 __attribute__((ext_vector_type(8)));
typedef float floatx4 __attribute__((ext_vector_type(4)));

__device__ __forceinline__ unsigned short f2bf(float f) {
  unsigned u = __float_as_uint(f);
  return (unsigned short)((u + 0x7FFF + ((u >> 16) & 1)) >> 16);  // RNE
}
__device__ __forceinline__ float bf2f(unsigned short h) {
  return __uint_as_float(((unsigned)h) << 16);
}

// ---------------- CSR build ----------------
__global__ __launch_bounds__(256) void k_deg_init(int* deg, int n) {
  int i = blockIdx.x * 256 + threadIdx.x;
  if (i < n) deg[i] = 1;  // self loop
}

__global__ __launch_bounds__(256) void k_count(const int* __restrict__ ei, int E, int* deg) {
  int i = blockIdx.x * 256 + threadIdx.x;
  if (i < E) atomicAdd(&deg[ei[E + i]], 1);
}

__device__ __forceinline__ int block_excl_scan(int v, int* tot) {
  __shared__ int wsum[4];
  int lane = threadIdx.x & 63, w = threadIdx.x >> 6;
  int x = v;
  #pragma unroll
  for (int off = 1; off < 64; off <<= 1) {
    int y = __shfl_up(x, off);
    if (lane >= off) x += y;
  }
  if (lane == 63) wsum[w] = x;
  __syncthreads();
  int wbase = 0;
  #pragma unroll
  for (int i = 0; i < 4; i++) wbase += (i < w) ? wsum[i] : 0;
  if (tot) *tot = wsum[0] + wsum[1] + wsum[2] + wsum[3];
  return wbase + x - v;
}

__global__ __launch_bounds__(256) void k_bsum(const int* __restrict__ deg, int* __restrict__ bsum, int n) {
  int i = blockIdx.x * 256 + threadIdx.x;
  int v = (i < n) ? deg[i] : 0;
  int tot;
  block_excl_scan(v, &tot);
  if (threadIdx.x == 0) bsum[blockIdx.x] = tot;
}

__global__ __launch_bounds__(256) void k_bscan(const int* __restrict__ bsum, int* __restrict__ boff, int nb) {
  int t = threadIdx.x;
  int v = (t < nb) ? bsum[t] : 0;
  int ex = block_excl_scan(v, nullptr);
  if (t < nb) boff[t] = ex;
}

__global__ __launch_bounds__(256) void k_rowptr(const int* __restrict__ deg,
                                                const int* __restrict__ boff,
                                                int* __restrict__ row_ptr,
                                                int* __restrict__ cursor, int n) {
  int i = blockIdx.x * 256 + threadIdx.x;
  int v = (i < n) ? deg[i] : 0;
  int ex = block_excl_scan(v, nullptr) + boff[blockIdx.x];
  if (i < n) { row_ptr[i] = ex; cursor[i] = ex; }
  if (i == n - 1) row_ptr[n] = ex + v;
}

__global__ __launch_bounds__(256) void k_fill(const int* __restrict__ ei, int E, int n,
                                              int* cursor, int* __restrict__ srcs) {
  int i = blockIdx.x * 256 + threadIdx.x;
  if (i >= E + n) return;
  int s, d;
  if (i < E) { s = ei[i]; d = ei[E + i]; }
  else       { s = i - E; d = s; }
  int slot = atomicAdd(&cursor[d], 1);
  srcs[slot] = s;
}

// ---------------- fp32 -> split-bf16 planes (x input) ----------------
__global__ __launch_bounds__(256) void k_cvt(const float* __restrict__ x,
                                             unsigned short* __restrict__ hi,
                                             unsigned short* __restrict__ lo, int n4) {
  int i = blockIdx.x * 256 + threadIdx.x;
  if (i >= n4) return;
  float4 v = ((const float4*)x)[i];
  ushort4 h, l;
  h.x = f2bf(v.x); l.x = f2bf(v.x - bf2f(h.x));
  h.y = f2bf(v.y); l.y = f2bf(v.y - bf2f(h.y));
  h.z = f2bf(v.z); l.z = f2bf(v.z - bf2f(h.z));
  h.w = f2bf(v.w); l.w = f2bf(v.w - bf2f(h.w));
  ((ushort4*)hi)[i] = h;
  ((ushort4*)lo)[i] = l;
}

// ---------------------------------------------------------------------------
// Weight prep for ALL layers, one launch. Swizzled elem (n, k):
//   nt=n/16, lr=n%16, j=k/32, kb=(k%32)/8, e=k%8
//   off = ((j*9+nt)*64 + kb*16+lr)*8 + e    (B-frag = contiguous 1KB)
// Per layer: 96 blocks. Blocks 0..63: transpose/split W (1 elem/thread).
// Blocks 64..95: projection cols, one wave per k-row, segmented shfl reduce.
// ---------------------------------------------------------------------------
struct WArgs {
  const float* W[6];
  const float* as[6];
  const float* ad[6];
  int H[6];
};

__global__ __launch_bounds__(256) void k_cvt_w_all(WArgs wa,
                                                   unsigned short* __restrict__ hiA,
                                                   unsigned short* __restrict__ loA) {
  int l = blockIdx.x / 96;
  int b = blockIdx.x % 96;
  const float* W = wa.W[l];
  unsigned short* hi2 = hiA + l * 144 * 128;
  unsigned short* lo2 = loA + l * 144 * 128;
  int H = wa.H[l];
  if (b < 64) {
    int i = b * 256 + threadIdx.x;       // one W element each
    int k = i >> 7, n = i & 127;
    float v = W[i];                      // coalesced
    unsigned short hh = f2bf(v), ll = f2bf(v - bf2f(hh));
    int nt = n >> 4, lr = n & 15;
    int j = k >> 5, kb = (k >> 3) & 3, e = k & 7;
    int off = ((j * 9 + nt) * 64 + kb * 16 + lr) * 8 + e;
    hi2[off] = hh; lo2[off] = ll;
    return;
  }
  if (H <= 0) return;
  const float* a_s = wa.as[l];
  const float* a_d = wa.ad[l];
  int w = (b - 64) * 4 + (threadIdx.x >> 6);   // k-row 0..127
  int lane = threadIdx.x & 63;
  int c0 = lane * 2;
  float2 wv = *(const float2*)(W + w * 128 + c0);
  float2 as2 = *(const float2*)(a_s + c0);
  float2 ad2 = *(const float2*)(a_d + c0);
  float ps = wv.x * as2.x + wv.y * as2.y;
  float pd = wv.x * ad2.x + wv.y * ad2.y;
  int C = 128 / H;
  int CL = C >> 1;                             // lanes per head segment
  for (int off = 1; off < CL; off <<= 1) {
    ps += __shfl_xor(ps, off);
    pd += __shfl_xor(pd, off);
  }
  if ((lane & (CL - 1)) == 0) {
    int hh = lane / CL;                        // head index
    int j = w >> 5, kb = (w >> 3) & 3, e = w & 7;
    int base = ((j * 9 + 8) * 64 + kb * 16) * 8 + e;   // nt=8, lr=0
    unsigned short hsv = f2bf(ps), lsv = f2bf(ps - bf2f(hsv));
    unsigned short hdv = f2bf(pd), ldv = f2bf(pd - bf2f(hdv));
    hi2[base + hh * 8] = hsv;       lo2[base + hh * 8] = lsv;
    hi2[base + (H + hh) * 8] = hdv; lo2[base + (H + hh) * 8] = ldv;
  }
}

// ---------------------------------------------------------------------------
// C[M,128] = A[M,128] @ W (+bias,+relu), als/ald from ext tile nt=8.
// Wt staged into LDS in 2 K-phases; MFMA loop reads LDS only.
// mfma_f32_16x16x32_bf16: A[lane&15][(lane>>4)*8+i], B[(lane>>4)*8+i][lane&15],
// C col=lane&15, row=(lane>>4)*4+reg (m89-verified layout).
// ---------------------------------------------------------------------------
__global__ __launch_bounds__(256) void k_gemm_bf(const unsigned short* __restrict__ Ahi,
                                                 const unsigned short* __restrict__ Alo,
                                                 const unsigned short* __restrict__ hi2,
                                                 const unsigned short* __restrict__ lo2,
                                                 const float* __restrict__ bias,
                                                 float* __restrict__ C,
                                                 float* __restrict__ als,
                                                 float* __restrict__ ald,
                                                 int M, int H, int relu) {
  __shared__ unsigned short lHi[9216];
  __shared__ unsigned short lLo[9216];
  int tid = threadIdx.x;
  int lane = tid & 63;
  int wv = tid >> 6;
  int m0 = blockIdx.x * 64 + wv * 16;
  int lr = lane & 15;
  int kb = lane >> 4;
  int arow = m0 + lr; if (arow >= M) arow = M - 1;   // clamp (stores guarded)
  const size_t abase = (size_t)arow * 128;

  short8 ahi[4], alo[4];
  #pragma unroll
  for (int j = 0; j < 4; j++) {
    int k0 = j * 32 + kb * 8;
    ahi[j] = *(const short8*)(Ahi + abase + k0);
    alo[j] = *(const short8*)(Alo + abase + k0);
  }

  floatx4 acc[9];
  #pragma unroll
  for (int nt = 0; nt < 9; nt++) acc[nt] = (floatx4){0.f, 0.f, 0.f, 0.f};

  #pragma unroll
  for (int p = 0; p < 2; p++) {
    if (p) __syncthreads();
    for (int ci = tid; ci < 1152; ci += 256) {
      ((short8*)lHi)[ci] = ((const short8*)(hi2 + p * 9216))[ci];
      ((short8*)lLo)[ci] = ((const short8*)(lo2 + p * 9216))[ci];
    }
    __syncthreads();
    #pragma unroll
    for (int jj = 0; jj < 2; jj++) {
      int j = p * 2 + jj;
      #pragma unroll
      for (int nt = 0; nt < 9; nt++) {
        int boff = ((jj * 9 + nt) * 64 + lane) * 8;
        short8 bhi = *(const short8*)(lHi + boff);
        short8 blo = *(const short8*)(lLo + boff);
        acc[nt] = __builtin_amdgcn_mfma_f32_16x16x32_bf16(ahi[j], bhi, acc[nt], 0, 0, 0);
        acc[nt] = __builtin_amdgcn_mfma_f32_16x16x32_bf16(ahi[j], blo, acc[nt], 0, 0, 0);
        acc[nt] = __builtin_amdgcn_mfma_f32_16x16x32_bf16(alo[j], bhi, acc[nt], 0, 0, 0);
      }
    }
  }

  #pragma unroll
  for (int nt = 0; nt < 8; nt++) {
    int col = nt * 16 + lr;
    #pragma unroll
    for (int r = 0; r < 4; r++) {
      int row = m0 + kb * 4 + r;
      if (row < M) {
        float v = acc[nt][r];
        if (bias) v += bias[col];
        if (relu) v = fmaxf(v, 0.f);
        C[(size_t)row * 128 + col] = v;
      }
    }
  }
  if (als) {
    #pragma unroll
    for (int r = 0; r < 4; r++) {
      int row = m0 + kb * 4 + r;
      if (row < M) {
        float v = acc[8][r];
        if (H == 8) {
          if (lr < 8) als[row * 8 + lr] = v;
          else        ald[row * 8 + (lr - 8)] = v;
        } else {
          if (lr == 0) als[row] = v;
          else if (lr == 1) ald[row] = v;
        }
      }
    }
  }
}

// ---------------------------------------------------------------------------
// Fused per-node softmax + aggregation. One wave per destination node.
// pass 1: per-(edge,head) logits -> LDS (deg<=128), online (m,d) reduce.
// pass 1.5: LDS e -> alpha in place (exp once per (edge,head)).
// pass 2: 4 edge slots x 16 lanes x 32B (2 float4), 2x unrolled -> 8 rows
//         in flight; alpha via LDS; slot-merge shfl_xor(16,32).
// ---------------------------------------------------------------------------
template <int H>
__global__ __launch_bounds__(256) void k_agg(const int* __restrict__ row_ptr,
                                             const int* __restrict__ srcs,
                                             const float* __restrict__ als,
                                             const float* __restrict__ ald,
                                             const float* __restrict__ h,
                                             const float* __restrict__ bias,
                                             unsigned short* __restrict__ outHi,
                                             unsigned short* __restrict__ outLo, int n) {
  __shared__ float eL[4][128 * H];
  __shared__ int svL[4][128];
  const int EPP = 64 / H;
  int lane = threadIdx.x & 63;
  int wv = threadIdx.x >> 6;
  int v = blockIdx.x * 4 + wv;
  bool active = (v < n);
  int s0 = 0, s1 = 0;
  int eo = lane / H;
  int hd = lane % H;
  float ed = 0.f;
  if (active) { s0 = row_ptr[v]; s1 = row_ptr[v + 1]; ed = ald[v * H + hd]; }
  // pass 1: logits -> LDS, online (m,d)
  float m = -1e30f, d = 0.f;
  for (int j = s0 + eo; j < s1; j += EPP) {
    int sv = srcs[j];
    float e = als[sv * H + hd] + ed;
    e = (e > 0.f) ? e : 0.2f * e;
    int idx = j - s0;
    if (idx < 128) {
      eL[wv][idx * H + hd] = e;
      if (hd == 0) svL[wv][idx] = sv;
    }
    float nm = fmaxf(m, e);
    d = d * __expf(m - nm) + __expf(e - nm);
    m = nm;
  }
  #pragma unroll
  for (int off = H; off < 64; off <<= 1) {
    float om = __shfl_xor(m, off);
    float od = __shfl_xor(d, off);
    float nm = fmaxf(m, om);
    d = d * __expf(m - nm) + od * __expf(om - nm);
    m = nm;
  }
  float inv = 1.f / d;  // d >= 1 (self loop)
  // pass 1.5: e -> alpha in place (t % H == hd since H divides 64)
  int nE = min(s1 - s0, 128);
  for (int t = lane; t < nE * H; t += 64)
    eL[wv][t] = __expf(eL[wv][t] - m) * inv;
  // pass 2: 4 slots x 16 lanes x 32B; 2x unroll -> 8 rows in flight
  int slot = lane >> 4;          // 0..3
  int l4 = lane & 15;
  int c0 = l4 * 8;               // channels c0..c0+7 (one 16-wide head holds 2 lanes)
  int hd2 = (H == 8) ? (l4 >> 1) : 0;
  float m2 = __shfl(m, hd2), inv2 = __shfl(inv, hd2), ed2 = __shfl(ed, hd2);
  float a0 = 0.f, a1 = 0.f, a2 = 0.f, a3 = 0.f;
  float a4 = 0.f, a5 = 0.f, a6 = 0.f, a7 = 0.f;
  int jj = slot;
  for (; jj + 4 < nE; jj += 8) {
    int sv0 = svL[wv][jj], sv1 = svL[wv][jj + 4];
    float al0 = eL[wv][jj * H + hd2], al1 = eL[wv][(jj + 4) * H + hd2];
    const float4* r0 = (const float4*)(h + (size_t)sv0 * 128 + c0);
    const float4* r1 = (const float4*)(h + (size_t)sv1 * 128 + c0);
    float4 p0 = r0[0], q0 = r0[1];
    float4 p1 = r1[0], q1 = r1[1];
    a0 += al0 * p0.x + al1 * p1.x;  a1 += al0 * p0.y + al1 * p1.y;
    a2 += al0 * p0.z + al1 * p1.z;  a3 += al0 * p0.w + al1 * p1.w;
    a4 += al0 * q0.x + al1 * q1.x;  a5 += al0 * q0.y + al1 * q1.y;
    a6 += al0 * q0.z + al1 * q1.z;  a7 += al0 * q0.w + al1 * q1.w;
  }
  for (; jj < nE; jj += 4) {
    int sv0 = svL[wv][jj];
    float al0 = eL[wv][jj * H + hd2];
    const float4* r0 = (const float4*)(h + (size_t)sv0 * 128 + c0);
    float4 p0 = r0[0], q0 = r0[1];
    a0 += al0 * p0.x; a1 += al0 * p0.y; a2 += al0 * p0.z; a3 += al0 * p0.w;
    a4 += al0 * q0.x; a5 += al0 * q0.y; a6 += al0 * q0.z; a7 += al0 * q0.w;
  }
  for (int j = s0 + 128 + slot; j < s1; j += 4) {  // rare tail (deg>128)
    int sv = srcs[j];
    float e = als[sv * H + hd2] + ed2;
    e = (e > 0.f) ? e : 0.2f * e;
    float al = __expf(e - m2) * inv2;
    const float4* r0 = (const float4*)(h + (size_t)sv * 128 + c0);
    float4 p0 = r0[0], q0 = r0[1];
    a0 += al * p0.x; a1 += al * p0.y; a2 += al * p0.z; a3 += al * p0.w;
    a4 += al * q0.x; a5 += al * q0.y; a6 += al * q0.z; a7 += al * q0.w;
  }
  #pragma unroll
  for (int off = 16; off < 64; off <<= 1) {
    a0 += __shfl_xor(a0, off); a1 += __shfl_xor(a1, off);
    a2 += __shfl_xor(a2, off); a3 += __shfl_xor(a3, off);
    a4 += __shfl_xor(a4, off); a5 += __shfl_xor(a5, off);
    a6 += __shfl_xor(a6, off); a7 += __shfl_xor(a7, off);
  }
  if (active && slot == 0) {
    float o[8] = {a0, a1, a2, a3, a4, a5, a6, a7};
    ushort4 h4a, l4a, h4b, l4b;
    #pragma unroll
    for (int e = 0; e < 8; e++) o[e] = fmaxf(o[e] + bias[c0 + e], 0.f);
    h4a.x = f2bf(o[0]); l4a.x = f2bf(o[0] - bf2f(h4a.x));
    h4a.y = f2bf(o[1]); l4a.y = f2bf(o[1] - bf2f(h4a.y));
    h4a.z = f2bf(o[2]); l4a.z = f2bf(o[2] - bf2f(h4a.z));
    h4a.w = f2bf(o[3]); l4a.w = f2bf(o[3] - bf2f(h4a.w));
    h4b.x = f2bf(o[4]); l4b.x = f2bf(o[4] - bf2f(h4b.x));
    h4b.y = f2bf(o[5]); l4b.y = f2bf(o[5] - bf2f(h4b.y));
    h4b.z = f2bf(o[6]); l4b.z = f2bf(o[6] - bf2f(h4b.z));
    h4b.w = f2bf(o[7]); l4b.w = f2bf(o[7] - bf2f(h4b.w));
    *(ushort4*)(outHi + (size_t)v * 128 + c0) = h4a;
    *(ushort4*)(outHi + (size_t)v * 128 + c0 + 4) = h4b;
    *(ushort4*)(outLo + (size_t)v * 128 + c0) = l4a;
    *(ushort4*)(outLo + (size_t)v * 128 + c0 + 4) = l4b;
  }
}

extern "C" void kernel_launch(void* const* d_in, const int* in_sizes, int n_in,
                              void* d_out, int out_size, void* d_ws, size_t ws_size,
                              hipStream_t stream) {
  const float* x  = (const float*)d_in[0];
  const int*   ei = (const int*)d_in[1];
  const int N  = in_sizes[0] / 128;
  const int E  = in_sizes[1] / 2;
  const int ET = E + N;
  const int NB = (N + 255) / 256;

  const float *Wl[5], *as[5], *ad[5], *bl[5];
  for (int l = 0; l < 5; l++) {
    Wl[l] = (const float*)d_in[3 + 4 * l];
    as[l] = (const float*)d_in[4 + 4 * l];
    ad[l] = (const float*)d_in[5 + 4 * l];
    bl[l] = (const float*)d_in[6 + 4 * l];
  }
  const float* W_lin = (const float*)d_in[23];
  const float* b_lin = (const float*)d_in[24];

  char* p = (char*)d_ws;
  auto alloc = [&](size_t bytes) { void* r = (void*)p; p += (bytes + 255) & ~size_t(255); return r; };
  float* h    = (float*)alloc((size_t)N * 128 * 4);
  unsigned short* pAhi = (unsigned short*)alloc((size_t)N * 128 * 2);
  unsigned short* pAlo = (unsigned short*)alloc((size_t)N * 128 * 2);
  unsigned short* pBhi = (unsigned short*)alloc((size_t)N * 128 * 2);
  unsigned short* pBlo = (unsigned short*)alloc((size_t)N * 128 * 2);
  unsigned short* WtHiA = (unsigned short*)alloc((size_t)6 * 144 * 128 * 2);
  unsigned short* WtLoA = (unsigned short*)alloc((size_t)6 * 144 * 128 * 2);
  float* als  = (float*)alloc((size_t)N * 8 * 4);
  float* ald  = (float*)alloc((size_t)N * 8 * 4);
  int* row_ptr = (int*)alloc((size_t)(N + 1) * 4);
  int* cursor  = (int*)alloc((size_t)N * 4);
  int* deg     = (int*)alloc((size_t)N * 4);
  int* srcs    = (int*)alloc((size_t)ET * 4);
  int* bsum    = (int*)alloc((size_t)NB * 4);
  int* boff    = (int*)alloc((size_t)NB * 4);
  (void)ws_size; (void)n_in; (void)out_size;

  dim3 b256(256);
  // All 6 weight conversions up front (one launch)
  WArgs wa;
  for (int l = 0; l < 5; l++) { wa.W[l] = Wl[l]; wa.as[l] = as[l]; wa.ad[l] = ad[l]; wa.H[l] = (l < 4) ? 8 : 1; }
  wa.W[5] = W_lin; wa.as[5] = nullptr; wa.ad[5] = nullptr; wa.H[5] = 0;
  k_cvt_w_all<<<576, b256, 0, stream>>>(wa, WtHiA, WtLoA);

  // CSR build (once; reused across all 5 layers)
  k_deg_init<<<NB, b256, 0, stream>>>(deg, N);
  k_count<<<(E + 255) / 256, b256, 0, stream>>>(ei, E, deg);
  k_bsum<<<NB, b256, 0, stream>>>(deg, bsum, N);
  k_bscan<<<1, b256, 0, stream>>>(bsum, boff, NB);
  k_rowptr<<<NB, b256, 0, stream>>>(deg, boff, row_ptr, cursor, N);
  k_fill<<<(ET + 255) / 256, b256, 0, stream>>>(ei, E, N, cursor, srcs);

  // x -> split-bf16 planes
  int n4 = N * 128 / 4;
  k_cvt<<<(n4 + 255) / 256, b256, 0, stream>>>(x, pAhi, pAlo, n4);

  int gemm_grid = (N + 63) / 64;
  unsigned short *inHi = pAhi, *inLo = pAlo, *outHi = pBhi, *outLo = pBlo;
  for (int l = 0; l < 5; l++) {
    int H = (l < 4) ? 8 : 1;
    k_gemm_bf<<<gemm_grid, b256, 0, stream>>>(inHi, inLo,
                                              WtHiA + l * 144 * 128, WtLoA + l * 144 * 128,
                                              nullptr, h, als, ald, N, H, 0);
    if (l < 4)
      k_agg<8><<<(N + 3) / 4, b256, 0, stream>>>(row_ptr, srcs, als, ald, h, bl[l], outHi, outLo, N);
    else
      k_agg<1><<<(N + 3) / 4, b256, 0, stream>>>(row_ptr, srcs, als, ald, h, bl[l], outHi, outLo, N);
    unsigned short* t;
    t = inHi; inHi = outHi; outHi = t;
    t = inLo; inLo = outLo; outLo = t;
  }
  k_gemm_bf<<<gemm_grid, b256, 0, stream>>>(inHi, inLo,
                                            WtHiA + 5 * 144 * 128, WtLoA + 5 * 144 * 128,
                                            b_lin, (float*)d_out, nullptr, nullptr, N, 0, 1);
}